// Round 8
// baseline (355.517 us; speedup 1.0000x reference)
//
#include <hip/hip_runtime.h>

typedef unsigned short u16;
typedef unsigned int u32;
typedef __attribute__((ext_vector_type(8))) short bf16x8;
typedef __attribute__((ext_vector_type(4))) float f32x4;

#define NQ 4096      // B*N query tokens
#define NKV 1024     // B*M kv tokens
#define CDIM 2048
#define NHEADS 16
#define HDIM 128
#define QSCALE 0.08838834764831843f  // 1/sqrt(128)

#define GLOAD_LDS16(g, l) __builtin_amdgcn_global_load_lds( \
    (const __attribute__((address_space(1))) unsigned int*)(g), \
    (__attribute__((address_space(3))) unsigned int*)(l), 16, 0, 0)

#define BARRIER() __builtin_amdgcn_s_barrier()
#define VMCNT(n) asm volatile("s_waitcnt vmcnt(" #n ")" ::: "memory")
#define LGKM0() asm volatile("s_waitcnt lgkmcnt(0)" ::: "memory")

__device__ __forceinline__ u16 f2bf(float f) {
  union { float f; u32 u; } a; a.f = f;
  u32 r = (a.u + 0x7fffu + ((a.u >> 16) & 1u)) >> 16;   // RNE
  return (u16)r;
}

// ---------------- fused prep: convert x/cond to bf16, transpose Wq/Wkv, zero vmax --
__global__ __launch_bounds__(256) void k_prep(const float* __restrict__ x,
                                              const float* __restrict__ cond,
                                              const float* __restrict__ Wq,
                                              const float* __restrict__ Wkv,
                                              u16* __restrict__ Xb,
                                              u16* __restrict__ Cb,
                                              u16* __restrict__ WqT,
                                              u16* __restrict__ WkvT,
                                              u32* __restrict__ vmax) {
  __shared__ float tile[32][33];
  const int id = blockIdx.x;
  if (id < 10240) {
    const int nx = NQ * CDIM / 4;
    int i = id * 256 + threadIdx.x;
    const float* in; u16* out; int j;
    if (i < nx) { in = x; out = Xb; j = i; }
    else        { in = cond; out = Cb; j = i - nx; }
    float4 v = ((const float4*)in)[j];
    uint2 r;
    r.x = (u32)f2bf(v.x) | ((u32)f2bf(v.y) << 16);
    r.y = (u32)f2bf(v.z) | ((u32)f2bf(v.w) << 16);
    ((uint2*)out)[j] = r;
    return;
  }
  if (id >= 22528) {
    int i = (id - 22528) * 256 + threadIdx.x;
    if (i < CDIM) vmax[i] = 0u;
    return;
  }
  int id2 = id - 10240;
  const float* in; u16* out; int R, Ccols, bx, by;
  if (id2 < 4096) { in = Wq;  out = WqT;  R = 2048; Ccols = 2048; bx = id2 & 63;  by = id2 >> 6; }
  else            { int i = id2 - 4096; in = Wkv; out = WkvT; R = 2048; Ccols = 4096; bx = i & 127; by = i >> 7; }
  int c0 = bx * 32, r0 = by * 32;
  int tx = threadIdx.x & 31, ty = threadIdx.x >> 5;
#pragma unroll
  for (int i = 0; i < 4; ++i)
    tile[ty + i*8][tx] = in[(size_t)(r0 + ty + i*8) * Ccols + c0 + tx];
  __syncthreads();
#pragma unroll
  for (int i = 0; i < 4; ++i)
    out[(size_t)(c0 + ty + i*8) * R + r0 + tx] = f2bf(tile[tx][ty + i*8]);
}

// ======================================================================
// 256x256-tile, BK=64, 8-wave, 4-phase/K-tile bf16 GEMM core (R3-proven).
// XOR-swizzled LDS via pre-swizzled global source; counted vmcnt(4) at
// tile boundary (never 0 in steady state). Bit-identical MFMA K-order.
// ======================================================================
__device__ __forceinline__ void gemm256_core(const u16* __restrict__ Ap,
                                             const u16* __restrict__ Bp,
                                             int lda, int ldb, int NT,
                                             u16* __restrict__ la0, u16* __restrict__ la1,
                                             u16* __restrict__ lb0, u16* __restrict__ lb1,
                                             f32x4 (&acc)[8][4]) {
  const int tid = threadIdx.x;
  const int lane = tid & 63, w = tid >> 6, quad = lane >> 4, l16 = lane & 15;
  const int wr = w >> 2, wc = w & 3;
  const int xo = (l16 & 7) << 4;                 // ds_read byte XOR
  const int rA = tid >> 3;                       // staging row 0..63 within half
  const int cbu = ((((tid & 7) << 4) ^ ((rA & 7) << 4)) >> 1);  // pre-swizzled src col (u16)

  bf16x8 a[4][2];
  bf16x8 bb[2][2][2];

#define STAGE(P, ld, L, h, tt) do { \
    const u16* g0_ = (P) + (size_t)((h) * 128 + rA) * (ld) + (size_t)(tt) * 64 + cbu; \
    u16* l0_ = (L) + (h) * 8192 + w * 512; \
    GLOAD_LDS16(g0_, l0_); \
    GLOAD_LDS16(g0_ + (size_t)64 * (ld), l0_ + 4096); \
  } while (0)

#define RD_A(bufp, mh) { \
    _Pragma("unroll") for (int rf = 0; rf < 4; ++rf) \
      _Pragma("unroll") for (int ks = 0; ks < 2; ++ks) \
        a[rf][ks] = *(const bf16x8*)((const char*)(bufp) + \
          (size_t)(wr * 128 + (mh) * 64 + rf * 16 + l16) * 128 + ((ks * 64 + quad * 16) ^ xo)); }

#define RD_B(bufp, nh) { \
    _Pragma("unroll") for (int cf = 0; cf < 2; ++cf) \
      _Pragma("unroll") for (int ks = 0; ks < 2; ++ks) \
        bb[nh][cf][ks] = *(const bf16x8*)((const char*)(bufp) + \
          (size_t)(wc * 64 + (nh) * 32 + cf * 16 + l16) * 128 + ((ks * 64 + quad * 16) ^ xo)); }

#define MQ(mh, nh) { \
    __builtin_amdgcn_s_setprio(1); \
    _Pragma("unroll") for (int rf = 0; rf < 4; ++rf) \
      _Pragma("unroll") for (int cf = 0; cf < 2; ++cf) \
        _Pragma("unroll") for (int ks = 0; ks < 2; ++ks) \
          acc[(mh)*4+rf][(nh)*2+cf] = __builtin_amdgcn_mfma_f32_16x16x32_bf16( \
            a[rf][ks], bb[nh][cf][ks], acc[(mh)*4+rf][(nh)*2+cf], 0, 0, 0); \
    __builtin_amdgcn_s_setprio(0); }

  STAGE(Bp, ldb, lb0, 0, 0);
  STAGE(Bp, ldb, lb0, 1, 0);
  STAGE(Ap, lda, la0, 0, 0);
  STAGE(Ap, lda, la0, 1, 0);
  STAGE(Bp, ldb, lb1, 0, 1);
  STAGE(Bp, ldb, lb1, 1, 1);
  VMCNT(4);
  BARRIER();

  for (int t = 0; t < NT; ++t) {
    u16* Ab = (t & 1) ? la1 : la0;
    u16* Bb = (t & 1) ? lb1 : lb0;
    u16* An = (t & 1) ? la0 : la1;
    const bool s1 = (t + 1) < NT, s2 = (t + 2) < NT;
    // ph0
    RD_A(Ab, 0); RD_B(Bb, 0);
    if (s1) STAGE(Ap, lda, An, 0, t + 1);
    BARRIER(); LGKM0();
    MQ(0, 0);
    BARRIER();
    // ph1
    RD_B(Bb, 1);
    if (s1) STAGE(Ap, lda, An, 1, t + 1);
    BARRIER(); LGKM0();
    MQ(0, 1);
    BARRIER();
    // ph2
    RD_A(Ab, 1);
    if (s2) STAGE(Bp, ldb, Bb, 0, t + 2);
    BARRIER(); LGKM0();
    MQ(1, 1);
    BARRIER();
    // ph3
    if (s2) STAGE(Bp, ldb, Bb, 1, t + 2);
    MQ(1, 0);
    if (s2) { VMCNT(4); } else { VMCNT(0); }
    BARRIER();
  }
  VMCNT(0);
#undef STAGE
#undef RD_A
#undef RD_B
#undef MQ
}

// ---------------- bf16 MFMA GEMM (out-proj), BM=128 x BN=256, full K, direct out --
__global__ __launch_bounds__(512, 2) void k_gemm_bt(const u16* __restrict__ A,
                                                    const u16* __restrict__ Bt,
                                                    const float* __restrict__ bias,
                                                    float* __restrict__ Cout,
                                                    int Ndim, int Kdim) {
  __shared__ u16 la0[8192];
  __shared__ u16 la1[8192];
  __shared__ u16 lb0[16384];
  __shared__ u16 lb1[16384];
  const int bn = blockIdx.x, bm = blockIdx.y;
  const int tid = threadIdx.x;
  const int lane = tid & 63, w = tid >> 6, quad = lane >> 4, l16 = lane & 15;
  const int wr = w >> 2, wc = w & 3;
  const int xo = (l16 & 7) << 4;
  const int rA = tid >> 3;
  const int cbu = ((((tid & 7) << 4) ^ ((rA & 7) << 4)) >> 1);

  const u16* Ap = A + (size_t)bm * 128 * Kdim;
  const u16* Bp = Bt + (size_t)bn * 256 * Kdim;
  const int NT = Kdim >> 6;

  f32x4 acc[4][4];
#pragma unroll
  for (int i = 0; i < 4; ++i)
#pragma unroll
    for (int j = 0; j < 4; ++j) acc[i][j] = (f32x4){0.f, 0.f, 0.f, 0.f};

  bf16x8 a[4][2];
  bf16x8 bb[2][2][2];

#define STAGE_A(L, tt) do { \
    const u16* g0_ = Ap + (size_t)rA * Kdim + (size_t)(tt) * 64 + cbu; \
    u16* l0_ = (L) + w * 512; \
    GLOAD_LDS16(g0_, l0_); \
    GLOAD_LDS16(g0_ + (size_t)64 * Kdim, l0_ + 4096); \
  } while (0)

#define STAGE_B(L, h, tt) do { \
    const u16* g0_ = Bp + (size_t)((h) * 128 + rA) * Kdim + (size_t)(tt) * 64 + cbu; \
    u16* l0_ = (L) + (h) * 8192 + w * 512; \
    GLOAD_LDS16(g0_, l0_); \
    GLOAD_LDS16(g0_ + (size_t)64 * Kdim, l0_ + 4096); \
  } while (0)

#define RD_A2(bufp) { \
    _Pragma("unroll") for (int rf = 0; rf < 4; ++rf) \
      _Pragma("unroll") for (int ks = 0; ks < 2; ++ks) \
        a[rf][ks] = *(const bf16x8*)((const char*)(bufp) + \
          (size_t)(wr * 64 + rf * 16 + l16) * 128 + ((ks * 64 + quad * 16) ^ xo)); }

#define RD_B2(bufp, nh) { \
    _Pragma("unroll") for (int cf = 0; cf < 2; ++cf) \
      _Pragma("unroll") for (int ks = 0; ks < 2; ++ks) \
        bb[nh][cf][ks] = *(const bf16x8*)((const char*)(bufp) + \
          (size_t)(wc * 64 + (nh) * 32 + cf * 16 + l16) * 128 + ((ks * 64 + quad * 16) ^ xo)); }

#define MQ2(nh) { \
    __builtin_amdgcn_s_setprio(1); \
    _Pragma("unroll") for (int rf = 0; rf < 4; ++rf) \
      _Pragma("unroll") for (int cf = 0; cf < 2; ++cf) \
        _Pragma("unroll") for (int ks = 0; ks < 2; ++ks) \
          acc[rf][(nh)*2+cf] = __builtin_amdgcn_mfma_f32_16x16x32_bf16( \
            a[rf][ks], bb[nh][cf][ks], acc[rf][(nh)*2+cf], 0, 0, 0); \
    __builtin_amdgcn_s_setprio(0); }

  STAGE_A(la0, 0);
  STAGE_B(lb0, 0, 0);
  STAGE_B(lb0, 1, 0);
  STAGE_B(lb1, 0, 1);
  STAGE_B(lb1, 1, 1);
  VMCNT(4);
  BARRIER();

  for (int t = 0; t < NT; ++t) {
    u16* Ab = (t & 1) ? la1 : la0;
    u16* Bb = (t & 1) ? lb1 : lb0;
    u16* An = (t & 1) ? la0 : la1;
    const bool s1 = (t + 1) < NT, s2 = (t + 2) < NT;
    // ph0: read A(all) + B(nh0); stage A(t+1) -> other A buf; MFMA nh0
    RD_A2(Ab); RD_B2(Bb, 0);
    if (s1) STAGE_A(An, t + 1);
    BARRIER(); LGKM0();
    MQ2(0);
    BARRIER();
    // ph1: read B(nh1); all waves' Bb reads retired -> stage B(t+2) into Bb
    RD_B2(Bb, 1);
    LGKM0();
    BARRIER();
    if (s2) { STAGE_B(Bb, 0, t + 2); STAGE_B(Bb, 1, t + 2); }
    MQ2(1);
    if (s2) { VMCNT(4); } else { VMCNT(0); }
    BARRIER();
  }
  VMCNT(0);
#undef STAGE_A
#undef STAGE_B
#undef RD_A2
#undef RD_B2
#undef MQ2

#pragma unroll
  for (int mf = 0; mf < 4; ++mf) {
    int row = bm * 128 + wr * 64 + mf * 16 + quad * 4;
#pragma unroll
    for (int nf = 0; nf < 4; ++nf) {
      int col = bn * 256 + wc * 64 + nf * 16 + l16;
      float bv = bias[col];
#pragma unroll
      for (int r = 0; r < 4; ++r)
        Cout[(size_t)(row + r) * Ndim + col] = acc[mf][nf][r] + bv;
    }
  }
}

// ---------------- fused QKV projection GEMM + quant epilogue + V colmax + Wp filler --
__global__ __launch_bounds__(512, 2) void k_gemm_qkv(const u16* __restrict__ Xb,
                                                     const u16* __restrict__ Cb,
                                                     const u16* __restrict__ WqT,
                                                     const u16* __restrict__ WkvT,
                                                     const float* __restrict__ Wp,
                                                     const float* __restrict__ bq,
                                                     const float* __restrict__ bkv,
                                                     u16* __restrict__ Qq,
                                                     u16* __restrict__ Kq,
                                                     float* __restrict__ Vraw,
                                                     u16* __restrict__ WpT,
                                                     u32* __restrict__ vmax) {
  __shared__ u16 la0[16384];
  __shared__ u16 la1[16384];
  __shared__ u16 lb0[16384];
  __shared__ u16 lb1[16384];

  const int id = blockIdx.x;
  const int tid = threadIdx.x;

  if (id >= 192) {
    // ---- Wp transpose filler: 64 blocks x 16 tiles of 64x64 (73-pad: no conflicts) --
    int fid = id - 192;
    float (*ft)[73] = (float(*)[73])la0;   // 64x73 fp32 = 18.7KB, aliases GEMM LDS
    const int rr = tid >> 3, cb = (tid & 7) * 8;
    for (int i = 0; i < 16; ++i) {
      int tIdx = fid * 16 + i;
      int r0 = (tIdx >> 5) * 64, c0 = (tIdx & 31) * 64;
      __syncthreads();
#pragma unroll
      for (int j = 0; j < 2; ++j)
        *(float4*)&ft[rr][cb + j * 4] =
            *(const float4*)&Wp[(size_t)(r0 + rr) * 2048 + c0 + cb + j * 4];
      __syncthreads();
      u16 tmp[8];
#pragma unroll
      for (int j = 0; j < 8; ++j) tmp[j] = f2bf(ft[cb + j][rr]);
      *(uint4*)&WpT[(size_t)(c0 + rr) * 2048 + r0 + cb] = *(uint4*)tmp;
    }
    return;
  }

  const u16 *Ain; const u16 *Bt; const float* bias;
  u16* out16 = nullptr; float* outf = nullptr;
  int bm, bn, ostride, ocol;
  float premul = 1.0f;
  if (id < 128) {
    bm = id >> 3; bn = id & 7;
    Ain = Xb; Bt = WqT + (size_t)(bn * 256) * CDIM;
    bias = bq + bn * 256; out16 = Qq; ostride = CDIM; ocol = bn * 256;
    premul = QSCALE;
  } else if (id < 160) {
    int i2 = id - 128; bm = i2 >> 3; bn = i2 & 7;
    Ain = Cb; Bt = WkvT + (size_t)(bn * 256) * CDIM;
    bias = bkv + bn * 256; out16 = Kq; ostride = CDIM; ocol = bn * 256;
  } else {
    int i3 = id - 160; bm = i3 >> 3; bn = i3 & 7;
    Ain = Cb; Bt = WkvT + (size_t)(2048 + bn * 256) * CDIM;
    bias = bkv + 2048 + bn * 256; outf = Vraw; ostride = 2 * CDIM; ocol = 2048 + bn * 256;
  }

  f32x4 acc[8][4];
#pragma unroll
  for (int i = 0; i < 8; ++i)
#pragma unroll
    for (int j = 0; j < 4; ++j) acc[i][j] = (f32x4){0.f, 0.f, 0.f, 0.f};

  gemm256_core(Ain + (size_t)bm * 256 * CDIM, Bt, CDIM, CDIM, CDIM >> 6,
               la0, la1, lb0, lb1, acc);

  const int w = tid >> 6, lane = tid & 63, quad = lane >> 4, l16 = lane & 15;
  const int wr = w >> 2, wc = w & 3;

  float bv[4];
#pragma unroll
  for (int nf = 0; nf < 4; ++nf) bv[nf] = bias[wc * 64 + nf * 16 + l16];

  if (outf) {
    float cmax[4];
#pragma unroll
    for (int nf = 0; nf < 4; ++nf) cmax[nf] = 0.f;
#pragma unroll
    for (int mf = 0; mf < 8; ++mf) {
      int row = bm * 256 + wr * 128 + mf * 16 + quad * 4;
#pragma unroll
      for (int nf = 0; nf < 4; ++nf) {
        int col = ocol + wc * 64 + nf * 16 + l16;
#pragma unroll
        for (int r = 0; r < 4; ++r) {
          float v = acc[mf][nf][r] + bv[nf];
          outf[(size_t)(row + r) * ostride + col] = v;
          cmax[nf] = fmaxf(cmax[nf], fabsf(v));
        }
      }
    }
#pragma unroll
    for (int nf = 0; nf < 4; ++nf) {
      cmax[nf] = fmaxf(cmax[nf], __shfl_xor(cmax[nf], 16));
      cmax[nf] = fmaxf(cmax[nf], __shfl_xor(cmax[nf], 32));
    }
    if (quad == 0) {
#pragma unroll
      for (int nf = 0; nf < 4; ++nf)
        atomicMax(&vmax[(ocol - 2048) + wc * 64 + nf * 16 + l16],
                  __float_as_uint(cmax[nf]));
    }
    return;
  }

  // Q/K: fused per-row-128 symmetric int8 fake-quant
  float amax[8][4];
#pragma unroll
  for (int mf = 0; mf < 8; ++mf)
#pragma unroll
    for (int r = 0; r < 4; ++r) amax[mf][r] = 0.f;
#pragma unroll
  for (int mf = 0; mf < 8; ++mf)
#pragma unroll
    for (int nf = 0; nf < 4; ++nf)
#pragma unroll
      for (int r = 0; r < 4; ++r) {
        float v = (acc[mf][nf][r] + bv[nf]) * premul;
        acc[mf][nf][r] = v;
        amax[mf][r] = fmaxf(amax[mf][r], fabsf(v));
      }
#pragma unroll
  for (int off = 1; off < 16; off <<= 1)
#pragma unroll
    for (int mf = 0; mf < 8; ++mf)
#pragma unroll
      for (int r = 0; r < 4; ++r)
        amax[mf][r] = fmaxf(amax[mf][r], __shfl_xor(amax[mf][r], off));

  float (*rmax)[256] = (float(*)[256])(&la0[0]);
  if (l16 == 0)
#pragma unroll
    for (int mf = 0; mf < 8; ++mf)
#pragma unroll
      for (int r = 0; r < 4; ++r)
        rmax[wc][wr * 128 + mf * 16 + quad * 4 + r] = amax[mf][r];
  __syncthreads();

  const int g2 = (wc >> 1) << 1;
#pragma unroll
  for (int mf = 0; mf < 8; ++mf) {
    int rowl = wr * 128 + mf * 16 + quad * 4;
    int row = bm * 256 + rowl;
#pragma unroll
    for (int r = 0; r < 4; ++r) {
      float s = fmaxf(fmaxf(rmax[g2][rowl + r], rmax[g2 + 1][rowl + r]) * (1.f / 127.f), 1e-8f);
#pragma unroll
      for (int nf = 0; nf < 4; ++nf) {
        int col = ocol + wc * 64 + nf * 16 + l16;
        float q = fminf(fmaxf(rintf(acc[mf][nf][r] / s), -127.f), 127.f) * s;
        out16[(size_t)(row + r) * ostride + col] = f2bf(q);
      }
    }
  }
}

// ---------------- quantize V and write transposed: Vt[(h*128+d)][token] ----------------
__global__ __launch_bounds__(256) void k_vt_quant(const float* __restrict__ in,
                                                  const float* __restrict__ vmax,
                                                  u16* __restrict__ Vt) {
  __shared__ float tile[32][33];
  int c0 = blockIdx.x * 32;
  int t0 = blockIdx.y * 32;
  int tx = threadIdx.x & 31, ty = threadIdx.x >> 5;
#pragma unroll
  for (int i = 0; i < 4; ++i)
    tile[ty + i*8][tx] = in[(size_t)(t0 + ty + i*8) * 4096 + c0 + tx];
  __syncthreads();
#pragma unroll
  for (int i = 0; i < 4; ++i) {
    int d = ty + i*8;
    float s = fmaxf(vmax[c0 + d] * (1.f / 127.f), 1e-8f);
    float q = fminf(fmaxf(rintf(tile[tx][d] / s), -127.f), 127.f) * s;
    Vt[(size_t)(c0 + d) * 1024 + t0 + tx] = f2bf(q);
  }
}

// ---------------- merged attention: phase1 computes m,l (ex-k_attn_ml, bit-exact),
// ---------------- phase2 recomputes QK^T, u, PV (ex-k_attn_pv) -------------------
__global__ __launch_bounds__(256, 2) void k_attn(const u16* __restrict__ Qq,
                                                 const u16* __restrict__ Kq,
                                                 const u16* __restrict__ Vt,
                                                 u16* __restrict__ O) {
  __shared__ u16 Ks[2][64 * 128];  // dbuf, swizzle g^(tok&15), 32KB
  __shared__ u16 Vs[2][128 * 64];  // dbuf, swizzle g^(d&7),   32KB
  __shared__ u16 Ub[4 * 32 * 64];  // per-wave u tile, swizzle g^(q&7), 16KB

  const int h = blockIdx.y;
  const int r0 = blockIdx.x * 128;
  const int t = threadIdx.x;
  const int w = t >> 6, lane = t & 63, quad = lane >> 4, l16 = lane & 15;

  const u16* Qh = Qq + (size_t)(r0 + w * 32) * CDIM + h * HDIM;
  const u16* Kh = Kq + h * HDIM;
  const u16* Vh = Vt + (size_t)h * HDIM * NKV;

  bf16x8 qf[2][4];
#pragma unroll
  for (int ti = 0; ti < 2; ++ti)
#pragma unroll
    for (int ks = 0; ks < 4; ++ks)
      qf[ti][ks] = *(const bf16x8*)&Qh[(size_t)(ti * 16 + l16) * CDIM + ks * 32 + quad * 8];

  const int ktl = (w * 4) * 4 + (lane >> 4);
  const int kg = (lane & 15);
  const int vdl = (w * 4) * 8 + (lane >> 3);
  const int vg = (lane & 7);

#define STAGE_K(ck, b) { \
    _Pragma("unroll") for (int j = 0; j < 4; ++j) { \
      int tok = ktl + j * 4; \
      GLOAD_LDS16(Kh + (size_t)((ck) * 64 + tok) * CDIM + (kg ^ (tok & 15)) * 8, \
                  &Ks[b][(w * 4 + j) * 512]); \
    } }
#define STAGE_V(ck, b) { \
    _Pragma("unroll") for (int j = 0; j < 4; ++j) { \
      int dl = vdl + j * 8; \
      GLOAD_LDS16(Vh + (size_t)dl * NKV + (ck) * 64 + (vg ^ (dl & 7)) * 8, \
                  &Vs[b][(w * 4 + j) * 512]); \
    } }

  // ================= phase 1: row max m + online sum l (bit-exact ex-k_attn_ml) ====
  float m[8], l[8];
#pragma unroll
  for (int i = 0; i < 8; ++i) { m[i] = -3e38f; l[i] = 0.f; }

  STAGE_K(0, 0);
  for (int ck = 0; ck < 16; ++ck) {
    const int cur = ck & 1;
    if (ck + 1 < 16) { STAGE_K(ck + 1, cur ^ 1); VMCNT(4); }
    else             { VMCNT(0); }
    BARRIER();

    f32x4 s_acc[2][4];
#pragma unroll
    for (int ti = 0; ti < 2; ++ti)
#pragma unroll
      for (int tj = 0; tj < 4; ++tj) s_acc[ti][tj] = (f32x4){0.f, 0.f, 0.f, 0.f};
#pragma unroll
    for (int ks = 0; ks < 4; ++ks)
#pragma unroll
      for (int tj = 0; tj < 4; ++tj) {
        bf16x8 bk = *(const bf16x8*)&Ks[cur][(tj * 16 + l16) * 128 + (((ks * 4 + quad) ^ l16) << 3)];
        s_acc[0][tj] = __builtin_amdgcn_mfma_f32_16x16x32_bf16(qf[0][ks], bk, s_acc[0][tj], 0, 0, 0);
        s_acc[1][tj] = __builtin_amdgcn_mfma_f32_16x16x32_bf16(qf[1][ks], bk, s_acc[1][tj], 0, 0, 0);
      }

#pragma unroll
    for (int ti = 0; ti < 2; ++ti) {
      float cm[4];
#pragma unroll
      for (int r = 0; r < 4; ++r)
        cm[r] = fmaxf(fmaxf(s_acc[ti][0][r], s_acc[ti][1][r]),
                      fmaxf(s_acc[ti][2][r], s_acc[ti][3][r]));
#pragma unroll
      for (int off = 1; off < 16; off <<= 1)
#pragma unroll
        for (int r = 0; r < 4; ++r) cm[r] = fmaxf(cm[r], __shfl_xor(cm[r], off));
#pragma unroll
      for (int r = 0; r < 4; ++r) {
        float mn = fmaxf(m[ti*4 + r], cm[r]);
        l[ti*4 + r] *= __expf(m[ti*4 + r] - mn);
        m[ti*4 + r] = mn;
      }
      float cs[4];
#pragma unroll
      for (int r = 0; r < 4; ++r)
        cs[r] = __expf(s_acc[ti][0][r] - m[ti*4 + r]) + __expf(s_acc[ti][1][r] - m[ti*4 + r]) +
                __expf(s_acc[ti][2][r] - m[ti*4 + r]) + __expf(s_acc[ti][3][r] - m[ti*4 + r]);
#pragma unroll
      for (int off = 1; off < 16; off <<= 1)
#pragma unroll
        for (int r = 0; r < 4; ++r) cs[r] += __shfl_xor(cs[r], off);
#pragma unroll
      for (int r = 0; r < 4; ++r) l[ti*4 + r] += cs[r];
    }
    BARRIER();   // protect Ks[cur] before next stage overwrites it
  }

  float rinv[8];
#pragma unroll
  for (int i = 0; i < 8; ++i) rinv[i] = 1.f / (255.f * l[i]);

  // ================= phase 2: QK^T recompute, u, PV (ex-k_attn_pv) ================
  f32x4 o_acc[2][8];
#pragma unroll
  for (int ti = 0; ti < 2; ++ti)
#pragma unroll
    for (int tj = 0; tj < 8; ++tj) o_acc[ti][tj] = (f32x4){0.f, 0.f, 0.f, 0.f};

  STAGE_K(0, 0); STAGE_V(0, 0);
  for (int ck = 0; ck < 16; ++ck) {
    const int cur = ck & 1;
    if (ck + 1 < 16) { STAGE_K(ck + 1, cur ^ 1); STAGE_V(ck + 1, cur ^ 1); VMCNT(8); }
    else             { VMCNT(0); }
    BARRIER();

    f32x4 s_acc[2][4];
#pragma unroll
    for (int ti = 0; ti < 2; ++ti)
#pragma unroll
      for (int tj = 0; tj < 4; ++tj) s_acc[ti][tj] = (f32x4){0.f, 0.f, 0.f, 0.f};
#pragma unroll
    for (int ks = 0; ks < 4; ++ks)
#pragma unroll
      for (int tj = 0; tj < 4; ++tj) {
        bf16x8 bk = *(const bf16x8*)&Ks[cur][(tj * 16 + l16) * 128 + (((ks * 4 + quad) ^ l16) << 3)];
        s_acc[0][tj] = __builtin_amdgcn_mfma_f32_16x16x32_bf16(qf[0][ks], bk, s_acc[0][tj], 0, 0, 0);
        s_acc[1][tj] = __builtin_amdgcn_mfma_f32_16x16x32_bf16(qf[1][ks], bk, s_acc[1][tj], 0, 0, 0);
      }

#pragma unroll
    for (int ti = 0; ti < 2; ++ti)
#pragma unroll
      for (int tj = 0; tj < 4; ++tj)
#pragma unroll
        for (int r = 0; r < 4; ++r) {
          int ql = ti * 16 + quad * 4 + r;
          int tok = tj * 16 + l16;
          float u = rintf(255.f * __expf(s_acc[ti][tj][r] - m[ti*4 + r]));
          Ub[w * 2048 + ql * 64 + ((((tok >> 3) ^ (ql & 7)) << 3) | (tok & 7))] = f2bf(u);
        }
#pragma unroll
    for (int ks2 = 0; ks2 < 2; ++ks2) {
      bf16x8 au[2];
#pragma unroll
      for (int ti = 0; ti < 2; ++ti) {
        int ql = ti * 16 + l16;
        au[ti] = *(const bf16x8*)&Ub[w * 2048 + ql * 64 + (((ks2 * 4 + quad) ^ (l16 & 7)) << 3)];
      }
#pragma unroll
      for (int tj = 0; tj < 8; ++tj) {
        bf16x8 bv = *(const bf16x8*)&Vs[cur][(tj * 16 + l16) * 64 + (((ks2 * 4 + quad) ^ (l16 & 7)) << 3)];
        o_acc[0][tj] = __builtin_amdgcn_mfma_f32_16x16x32_bf16(au[0], bv, o_acc[0][tj], 0, 0, 0);
        o_acc[1][tj] = __builtin_amdgcn_mfma_f32_16x16x32_bf16(au[1], bv, o_acc[1][tj], 0, 0, 0);
      }
    }
    BARRIER();   // protect Ks/Vs[cur] before next stage overwrites it
  }
#undef STAGE_K
#undef STAGE_V

#pragma unroll
  for (int ti = 0; ti < 2; ++ti)
#pragma unroll
    for (int tj = 0; tj < 8; ++tj)
#pragma unroll
      for (int r = 0; r < 4; ++r) {
        int row = r0 + w * 32 + ti * 16 + quad * 4 + r;
        int d = tj * 16 + l16;
        O[(size_t)row * CDIM + h * HDIM + d] = f2bf(o_acc[ti][tj][r] * rinv[ti*4 + r]);
      }
}

extern "C" void kernel_launch(void* const* d_in, const int* in_sizes, int n_in,
                              void* d_out, int out_size, void* d_ws, size_t ws_size,
                              hipStream_t stream) {
  const float* x    = (const float*)d_in[0];
  const float* cond = (const float*)d_in[1];
  const float* Wq   = (const float*)d_in[2];
  const float* bq   = (const float*)d_in[3];
  const float* Wkv  = (const float*)d_in[4];
  const float* bkv  = (const float*)d_in[5];
  const float* Wp   = (const float*)d_in[6];
  const float* bp   = (const float*)d_in[7];
  float* out = (float*)d_out;

  char* ws = (char*)d_ws;
  size_t off = 0;
  auto alloc = [&](size_t bytes) -> char* {
    char* p = ws + off;
    off += (bytes + 255) & ~(size_t)255;
    return p;
  };
  u16*   Xb    = (u16*)alloc((size_t)NQ * CDIM * 2);
  u16*   Cb    = (u16*)alloc((size_t)NKV * CDIM * 2);
  u16*   WqT   = (u16*)alloc((size_t)CDIM * CDIM * 2);
  u16*   WkvT  = (u16*)alloc((size_t)2 * CDIM * CDIM * 2);
  float* KVraw = (float*)alloc((size_t)NKV * 2 * CDIM * 4);  // only V-half written
  u16*   Qq    = (u16*)alloc((size_t)NQ * CDIM * 2);
  u16*   Kq    = (u16*)alloc((size_t)NKV * CDIM * 2);
  u16*   Vt    = (u16*)alloc((size_t)CDIM * NKV * 2);
  float* vmax  = (float*)alloc((size_t)CDIM * 4);
  u16*   Ob    = (u16*)alloc((size_t)NQ * CDIM * 2);
  u16*   WpT   = (u16*)alloc((size_t)CDIM * CDIM * 2);

  k_prep<<<22536, 256, 0, stream>>>(x, cond, Wq, Wkv, Xb, Cb, WqT, WkvT, (u32*)vmax);
  k_gemm_qkv<<<256, 512, 0, stream>>>(Xb, Cb, WqT, WkvT, Wp, bq, bkv, Qq, Kq, KVraw,
                                      WpT, (u32*)vmax);
  k_vt_quant<<<dim3(CDIM/32, NKV/32), 256, 0, stream>>>(KVraw + CDIM, vmax, Vt);
  k_attn<<<dim3(NQ/128, NHEADS), 256, 0, stream>>>(Qq, Kq, Vt, Ob);
  k_gemm_bt<<<dim3(CDIM/256, NQ/128), 512, 0, stream>>>(Ob, WpT, bp, out, CDIM, CDIM);
}

// Round 9
// 339.033 us; speedup vs baseline: 1.0486x; 1.0486x over previous
//
#include <hip/hip_runtime.h>

typedef unsigned short u16;
typedef unsigned int u32;
typedef __attribute__((ext_vector_type(8))) short bf16x8;
typedef __attribute__((ext_vector_type(4))) float f32x4;

#define NQ 4096      // B*N query tokens
#define NKV 1024     // B*M kv tokens
#define CDIM 2048
#define NHEADS 16
#define HDIM 128
#define QSCALE 0.08838834764831843f  // 1/sqrt(128)

#define GLOAD_LDS16(g, l) __builtin_amdgcn_global_load_lds( \
    (const __attribute__((address_space(1))) unsigned int*)(g), \
    (__attribute__((address_space(3))) unsigned int*)(l), 16, 0, 0)

#define BARRIER() __builtin_amdgcn_s_barrier()
#define VMCNT(n) asm volatile("s_waitcnt vmcnt(" #n ")" ::: "memory")
#define LGKM0() asm volatile("s_waitcnt lgkmcnt(0)" ::: "memory")

__device__ __forceinline__ u16 f2bf(float f) {
  union { float f; u32 u; } a; a.f = f;
  u32 r = (a.u + 0x7fffu + ((a.u >> 16) & 1u)) >> 16;   // RNE
  return (u16)r;
}

// ---------------- fused prep: convert x/cond to bf16, transpose Wq/Wkv, zero vmax --
__global__ __launch_bounds__(256) void k_prep(const float* __restrict__ x,
                                              const float* __restrict__ cond,
                                              const float* __restrict__ Wq,
                                              const float* __restrict__ Wkv,
                                              u16* __restrict__ Xb,
                                              u16* __restrict__ Cb,
                                              u16* __restrict__ WqT,
                                              u16* __restrict__ WkvT,
                                              u32* __restrict__ vmax) {
  __shared__ float tile[32][33];
  const int id = blockIdx.x;
  if (id < 10240) {
    const int nx = NQ * CDIM / 4;
    int i = id * 256 + threadIdx.x;
    const float* in; u16* out; int j;
    if (i < nx) { in = x; out = Xb; j = i; }
    else        { in = cond; out = Cb; j = i - nx; }
    float4 v = ((const float4*)in)[j];
    uint2 r;
    r.x = (u32)f2bf(v.x) | ((u32)f2bf(v.y) << 16);
    r.y = (u32)f2bf(v.z) | ((u32)f2bf(v.w) << 16);
    ((uint2*)out)[j] = r;
    return;
  }
  if (id >= 22528) {
    int i = (id - 22528) * 256 + threadIdx.x;
    if (i < CDIM) vmax[i] = 0u;
    return;
  }
  int id2 = id - 10240;
  const float* in; u16* out; int R, Ccols, bx, by;
  if (id2 < 4096) { in = Wq;  out = WqT;  R = 2048; Ccols = 2048; bx = id2 & 63;  by = id2 >> 6; }
  else            { int i = id2 - 4096; in = Wkv; out = WkvT; R = 2048; Ccols = 4096; bx = i & 127; by = i >> 7; }
  int c0 = bx * 32, r0 = by * 32;
  int tx = threadIdx.x & 31, ty = threadIdx.x >> 5;
#pragma unroll
  for (int i = 0; i < 4; ++i)
    tile[ty + i*8][tx] = in[(size_t)(r0 + ty + i*8) * Ccols + c0 + tx];
  __syncthreads();
#pragma unroll
  for (int i = 0; i < 4; ++i)
    out[(size_t)(c0 + ty + i*8) * R + r0 + tx] = f2bf(tile[tx][ty + i*8]);
}

// ======================================================================
// 256x256-tile, BK=64, 8-wave, 4-phase/K-tile bf16 GEMM core (R3-proven).
// XOR-swizzled LDS via pre-swizzled global source; counted vmcnt(4) at
// tile boundary (never 0 in steady state). Bit-identical MFMA K-order.
// ======================================================================
__device__ __forceinline__ void gemm256_core(const u16* __restrict__ Ap,
                                             const u16* __restrict__ Bp,
                                             int lda, int ldb, int NT,
                                             u16* __restrict__ la0, u16* __restrict__ la1,
                                             u16* __restrict__ lb0, u16* __restrict__ lb1,
                                             f32x4 (&acc)[8][4]) {
  const int tid = threadIdx.x;
  const int lane = tid & 63, w = tid >> 6, quad = lane >> 4, l16 = lane & 15;
  const int wr = w >> 2, wc = w & 3;
  const int xo = (l16 & 7) << 4;                 // ds_read byte XOR
  const int rA = tid >> 3;                       // staging row 0..63 within half
  const int cbu = ((((tid & 7) << 4) ^ ((rA & 7) << 4)) >> 1);  // pre-swizzled src col (u16)

  bf16x8 a[4][2];
  bf16x8 bb[2][2][2];

#define STAGE(P, ld, L, h, tt) do { \
    const u16* g0_ = (P) + (size_t)((h) * 128 + rA) * (ld) + (size_t)(tt) * 64 + cbu; \
    u16* l0_ = (L) + (h) * 8192 + w * 512; \
    GLOAD_LDS16(g0_, l0_); \
    GLOAD_LDS16(g0_ + (size_t)64 * (ld), l0_ + 4096); \
  } while (0)

#define RD_A(bufp, mh) { \
    _Pragma("unroll") for (int rf = 0; rf < 4; ++rf) \
      _Pragma("unroll") for (int ks = 0; ks < 2; ++ks) \
        a[rf][ks] = *(const bf16x8*)((const char*)(bufp) + \
          (size_t)(wr * 128 + (mh) * 64 + rf * 16 + l16) * 128 + ((ks * 64 + quad * 16) ^ xo)); }

#define RD_B(bufp, nh) { \
    _Pragma("unroll") for (int cf = 0; cf < 2; ++cf) \
      _Pragma("unroll") for (int ks = 0; ks < 2; ++ks) \
        bb[nh][cf][ks] = *(const bf16x8*)((const char*)(bufp) + \
          (size_t)(wc * 64 + (nh) * 32 + cf * 16 + l16) * 128 + ((ks * 64 + quad * 16) ^ xo)); }

#define MQ(mh, nh) { \
    __builtin_amdgcn_s_setprio(1); \
    _Pragma("unroll") for (int rf = 0; rf < 4; ++rf) \
      _Pragma("unroll") for (int cf = 0; cf < 2; ++cf) \
        _Pragma("unroll") for (int ks = 0; ks < 2; ++ks) \
          acc[(mh)*4+rf][(nh)*2+cf] = __builtin_amdgcn_mfma_f32_16x16x32_bf16( \
            a[rf][ks], bb[nh][cf][ks], acc[(mh)*4+rf][(nh)*2+cf], 0, 0, 0); \
    __builtin_amdgcn_s_setprio(0); }

  STAGE(Bp, ldb, lb0, 0, 0);
  STAGE(Bp, ldb, lb0, 1, 0);
  STAGE(Ap, lda, la0, 0, 0);
  STAGE(Ap, lda, la0, 1, 0);
  STAGE(Bp, ldb, lb1, 0, 1);
  STAGE(Bp, ldb, lb1, 1, 1);
  VMCNT(4);
  BARRIER();

  for (int t = 0; t < NT; ++t) {
    u16* Ab = (t & 1) ? la1 : la0;
    u16* Bb = (t & 1) ? lb1 : lb0;
    u16* An = (t & 1) ? la0 : la1;
    const bool s1 = (t + 1) < NT, s2 = (t + 2) < NT;
    // ph0
    RD_A(Ab, 0); RD_B(Bb, 0);
    if (s1) STAGE(Ap, lda, An, 0, t + 1);
    BARRIER(); LGKM0();
    MQ(0, 0);
    BARRIER();
    // ph1
    RD_B(Bb, 1);
    if (s1) STAGE(Ap, lda, An, 1, t + 1);
    BARRIER(); LGKM0();
    MQ(0, 1);
    BARRIER();
    // ph2
    RD_A(Ab, 1);
    if (s2) STAGE(Bp, ldb, Bb, 0, t + 2);
    BARRIER(); LGKM0();
    MQ(1, 1);
    BARRIER();
    // ph3
    if (s2) STAGE(Bp, ldb, Bb, 1, t + 2);
    MQ(1, 0);
    if (s2) { VMCNT(4); } else { VMCNT(0); }
    BARRIER();
  }
  VMCNT(0);
#undef STAGE
#undef RD_A
#undef RD_B
#undef MQ
}

// ---------------- bf16 MFMA GEMM (out-proj), BM=128 x BN=256, full K, direct out --
__global__ __launch_bounds__(512, 2) void k_gemm_bt(const u16* __restrict__ A,
                                                    const u16* __restrict__ Bt,
                                                    const float* __restrict__ bias,
                                                    float* __restrict__ Cout,
                                                    int Ndim, int Kdim) {
  __shared__ u16 la0[8192];
  __shared__ u16 la1[8192];
  __shared__ u16 lb0[16384];
  __shared__ u16 lb1[16384];
  const int bn = blockIdx.x, bm = blockIdx.y;
  const int tid = threadIdx.x;
  const int lane = tid & 63, w = tid >> 6, quad = lane >> 4, l16 = lane & 15;
  const int wr = w >> 2, wc = w & 3;
  const int xo = (l16 & 7) << 4;
  const int rA = tid >> 3;
  const int cbu = ((((tid & 7) << 4) ^ ((rA & 7) << 4)) >> 1);

  const u16* Ap = A + (size_t)bm * 128 * Kdim;
  const u16* Bp = Bt + (size_t)bn * 256 * Kdim;
  const int NT = Kdim >> 6;

  f32x4 acc[4][4];
#pragma unroll
  for (int i = 0; i < 4; ++i)
#pragma unroll
    for (int j = 0; j < 4; ++j) acc[i][j] = (f32x4){0.f, 0.f, 0.f, 0.f};

  bf16x8 a[4][2];
  bf16x8 bb[2][2][2];

#define STAGE_A(L, tt) do { \
    const u16* g0_ = Ap + (size_t)rA * Kdim + (size_t)(tt) * 64 + cbu; \
    u16* l0_ = (L) + w * 512; \
    GLOAD_LDS16(g0_, l0_); \
    GLOAD_LDS16(g0_ + (size_t)64 * Kdim, l0_ + 4096); \
  } while (0)

#define STAGE_B(L, h, tt) do { \
    const u16* g0_ = Bp + (size_t)((h) * 128 + rA) * Kdim + (size_t)(tt) * 64 + cbu; \
    u16* l0_ = (L) + (h) * 8192 + w * 512; \
    GLOAD_LDS16(g0_, l0_); \
    GLOAD_LDS16(g0_ + (size_t)64 * Kdim, l0_ + 4096); \
  } while (0)

#define RD_A2(bufp) { \
    _Pragma("unroll") for (int rf = 0; rf < 4; ++rf) \
      _Pragma("unroll") for (int ks = 0; ks < 2; ++ks) \
        a[rf][ks] = *(const bf16x8*)((const char*)(bufp) + \
          (size_t)(wr * 64 + rf * 16 + l16) * 128 + ((ks * 64 + quad * 16) ^ xo)); }

#define RD_B2(bufp, nh) { \
    _Pragma("unroll") for (int cf = 0; cf < 2; ++cf) \
      _Pragma("unroll") for (int ks = 0; ks < 2; ++ks) \
        bb[nh][cf][ks] = *(const bf16x8*)((const char*)(bufp) + \
          (size_t)(wc * 64 + (nh) * 32 + cf * 16 + l16) * 128 + ((ks * 64 + quad * 16) ^ xo)); }

#define MQ2(nh) { \
    __builtin_amdgcn_s_setprio(1); \
    _Pragma("unroll") for (int rf = 0; rf < 4; ++rf) \
      _Pragma("unroll") for (int cf = 0; cf < 2; ++cf) \
        _Pragma("unroll") for (int ks = 0; ks < 2; ++ks) \
          acc[rf][(nh)*2+cf] = __builtin_amdgcn_mfma_f32_16x16x32_bf16( \
            a[rf][ks], bb[nh][cf][ks], acc[rf][(nh)*2+cf], 0, 0, 0); \
    __builtin_amdgcn_s_setprio(0); }

  STAGE_A(la0, 0);
  STAGE_B(lb0, 0, 0);
  STAGE_B(lb0, 1, 0);
  STAGE_B(lb1, 0, 1);
  STAGE_B(lb1, 1, 1);
  VMCNT(4);
  BARRIER();

  for (int t = 0; t < NT; ++t) {
    u16* Ab = (t & 1) ? la1 : la0;
    u16* Bb = (t & 1) ? lb1 : lb0;
    u16* An = (t & 1) ? la0 : la1;
    const bool s1 = (t + 1) < NT, s2 = (t + 2) < NT;
    // ph0: read A(all) + B(nh0); stage A(t+1) -> other A buf; MFMA nh0
    RD_A2(Ab); RD_B2(Bb, 0);
    if (s1) STAGE_A(An, t + 1);
    BARRIER(); LGKM0();
    MQ2(0);
    BARRIER();
    // ph1: read B(nh1); all waves' Bb reads retired -> stage B(t+2) into Bb
    RD_B2(Bb, 1);
    LGKM0();
    BARRIER();
    if (s2) { STAGE_B(Bb, 0, t + 2); STAGE_B(Bb, 1, t + 2); }
    MQ2(1);
    if (s2) { VMCNT(4); } else { VMCNT(0); }
    BARRIER();
  }
  VMCNT(0);
#undef STAGE_A
#undef STAGE_B
#undef RD_A2
#undef RD_B2
#undef MQ2

#pragma unroll
  for (int mf = 0; mf < 4; ++mf) {
    int row = bm * 128 + wr * 64 + mf * 16 + quad * 4;
#pragma unroll
    for (int nf = 0; nf < 4; ++nf) {
      int col = bn * 256 + wc * 64 + nf * 16 + l16;
      float bv = bias[col];
#pragma unroll
      for (int r = 0; r < 4; ++r)
        Cout[(size_t)(row + r) * Ndim + col] = acc[mf][nf][r] + bv;
    }
  }
}

// ---------------- fused QKV projection GEMM + quant epilogue + V colmax + Wp filler --
__global__ __launch_bounds__(512, 2) void k_gemm_qkv(const u16* __restrict__ Xb,
                                                     const u16* __restrict__ Cb,
                                                     const u16* __restrict__ WqT,
                                                     const u16* __restrict__ WkvT,
                                                     const float* __restrict__ Wp,
                                                     const float* __restrict__ bq,
                                                     const float* __restrict__ bkv,
                                                     u16* __restrict__ Qq,
                                                     u16* __restrict__ Kq,
                                                     float* __restrict__ Vraw,
                                                     u16* __restrict__ WpT,
                                                     u32* __restrict__ vmax) {
  __shared__ u16 la0[16384];
  __shared__ u16 la1[16384];
  __shared__ u16 lb0[16384];
  __shared__ u16 lb1[16384];

  const int id = blockIdx.x;
  const int tid = threadIdx.x;

  if (id >= 192) {
    // ---- Wp transpose filler: 64 blocks x 16 tiles of 64x64 (73-pad: no conflicts) --
    int fid = id - 192;
    float (*ft)[73] = (float(*)[73])la0;   // 64x73 fp32 = 18.7KB, aliases GEMM LDS
    const int rr = tid >> 3, cb = (tid & 7) * 8;
    for (int i = 0; i < 16; ++i) {
      int tIdx = fid * 16 + i;
      int r0 = (tIdx >> 5) * 64, c0 = (tIdx & 31) * 64;
      __syncthreads();
#pragma unroll
      for (int j = 0; j < 2; ++j)
        *(float4*)&ft[rr][cb + j * 4] =
            *(const float4*)&Wp[(size_t)(r0 + rr) * 2048 + c0 + cb + j * 4];
      __syncthreads();
      u16 tmp[8];
#pragma unroll
      for (int j = 0; j < 8; ++j) tmp[j] = f2bf(ft[cb + j][rr]);
      *(uint4*)&WpT[(size_t)(c0 + rr) * 2048 + r0 + cb] = *(uint4*)tmp;
    }
    return;
  }

  const u16 *Ain; const u16 *Bt; const float* bias;
  u16* out16 = nullptr; float* outf = nullptr;
  int bm, bn, ostride, ocol;
  float premul = 1.0f;
  if (id < 128) {
    bm = id >> 3; bn = id & 7;
    Ain = Xb; Bt = WqT + (size_t)(bn * 256) * CDIM;
    bias = bq + bn * 256; out16 = Qq; ostride = CDIM; ocol = bn * 256;
    premul = QSCALE;
  } else if (id < 160) {
    int i2 = id - 128; bm = i2 >> 3; bn = i2 & 7;
    Ain = Cb; Bt = WkvT + (size_t)(bn * 256) * CDIM;
    bias = bkv + bn * 256; out16 = Kq; ostride = CDIM; ocol = bn * 256;
  } else {
    int i3 = id - 160; bm = i3 >> 3; bn = i3 & 7;
    Ain = Cb; Bt = WkvT + (size_t)(2048 + bn * 256) * CDIM;
    bias = bkv + 2048 + bn * 256; outf = Vraw; ostride = 2 * CDIM; ocol = 2048 + bn * 256;
  }

  f32x4 acc[8][4];
#pragma unroll
  for (int i = 0; i < 8; ++i)
#pragma unroll
    for (int j = 0; j < 4; ++j) acc[i][j] = (f32x4){0.f, 0.f, 0.f, 0.f};

  gemm256_core(Ain + (size_t)bm * 256 * CDIM, Bt, CDIM, CDIM, CDIM >> 6,
               la0, la1, lb0, lb1, acc);

  const int w = tid >> 6, lane = tid & 63, quad = lane >> 4, l16 = lane & 15;
  const int wr = w >> 2, wc = w & 3;

  float bv[4];
#pragma unroll
  for (int nf = 0; nf < 4; ++nf) bv[nf] = bias[wc * 64 + nf * 16 + l16];

  if (outf) {
    float cmax[4];
#pragma unroll
    for (int nf = 0; nf < 4; ++nf) cmax[nf] = 0.f;
#pragma unroll
    for (int mf = 0; mf < 8; ++mf) {
      int row = bm * 256 + wr * 128 + mf * 16 + quad * 4;
#pragma unroll
      for (int nf = 0; nf < 4; ++nf) {
        int col = ocol + wc * 64 + nf * 16 + l16;
#pragma unroll
        for (int r = 0; r < 4; ++r) {
          float v = acc[mf][nf][r] + bv[nf];
          outf[(size_t)(row + r) * ostride + col] = v;
          cmax[nf] = fmaxf(cmax[nf], fabsf(v));
        }
      }
    }
#pragma unroll
    for (int nf = 0; nf < 4; ++nf) {
      cmax[nf] = fmaxf(cmax[nf], __shfl_xor(cmax[nf], 16));
      cmax[nf] = fmaxf(cmax[nf], __shfl_xor(cmax[nf], 32));
    }
    if (quad == 0) {
#pragma unroll
      for (int nf = 0; nf < 4; ++nf)
        atomicMax(&vmax[(ocol - 2048) + wc * 64 + nf * 16 + l16],
                  __float_as_uint(cmax[nf]));
    }
    return;
  }

  // Q/K: fused per-row-128 symmetric int8 fake-quant
  float amax[8][4];
#pragma unroll
  for (int mf = 0; mf < 8; ++mf)
#pragma unroll
    for (int r = 0; r < 4; ++r) amax[mf][r] = 0.f;
#pragma unroll
  for (int mf = 0; mf < 8; ++mf)
#pragma unroll
    for (int nf = 0; nf < 4; ++nf)
#pragma unroll
      for (int r = 0; r < 4; ++r) {
        float v = (acc[mf][nf][r] + bv[nf]) * premul;
        acc[mf][nf][r] = v;
        amax[mf][r] = fmaxf(amax[mf][r], fabsf(v));
      }
#pragma unroll
  for (int off = 1; off < 16; off <<= 1)
#pragma unroll
    for (int mf = 0; mf < 8; ++mf)
#pragma unroll
      for (int r = 0; r < 4; ++r)
        amax[mf][r] = fmaxf(amax[mf][r], __shfl_xor(amax[mf][r], off));

  float (*rmax)[256] = (float(*)[256])(&la0[0]);
  if (l16 == 0)
#pragma unroll
    for (int mf = 0; mf < 8; ++mf)
#pragma unroll
      for (int r = 0; r < 4; ++r)
        rmax[wc][wr * 128 + mf * 16 + quad * 4 + r] = amax[mf][r];
  __syncthreads();

  const int g2 = (wc >> 1) << 1;
#pragma unroll
  for (int mf = 0; mf < 8; ++mf) {
    int rowl = wr * 128 + mf * 16 + quad * 4;
    int row = bm * 256 + rowl;
#pragma unroll
    for (int r = 0; r < 4; ++r) {
      float s = fmaxf(fmaxf(rmax[g2][rowl + r], rmax[g2 + 1][rowl + r]) * (1.f / 127.f), 1e-8f);
#pragma unroll
      for (int nf = 0; nf < 4; ++nf) {
        int col = ocol + wc * 64 + nf * 16 + l16;
        float q = fminf(fmaxf(rintf(acc[mf][nf][r] / s), -127.f), 127.f) * s;
        out16[(size_t)(row + r) * ostride + col] = f2bf(q);
      }
    }
  }
}

// ---------------- quantize V and write transposed: Vt[(h*128+d)][token] ----------------
__global__ __launch_bounds__(256) void k_vt_quant(const float* __restrict__ in,
                                                  const float* __restrict__ vmax,
                                                  u16* __restrict__ Vt) {
  __shared__ float tile[32][33];
  int c0 = blockIdx.x * 32;
  int t0 = blockIdx.y * 32;
  int tx = threadIdx.x & 31, ty = threadIdx.x >> 5;
#pragma unroll
  for (int i = 0; i < 4; ++i)
    tile[ty + i*8][tx] = in[(size_t)(t0 + ty + i*8) * 4096 + c0 + tx];
  __syncthreads();
#pragma unroll
  for (int i = 0; i < 4; ++i) {
    int d = ty + i*8;
    float s = fmaxf(vmax[c0 + d] * (1.f / 127.f), 1e-8f);
    float q = fminf(fmaxf(rintf(tile[tx][d] / s), -127.f), 127.f) * s;
    Vt[(size_t)(c0 + d) * 1024 + t0 + tx] = f2bf(q);
  }
}

// ---------------- merged attention, phase-1-lite ----------------------------------
// phase1: QK^T -> row max m ONLY (no exp, no online sum — max is order-invariant).
// phase2: QK^T recompute; p = exp(s-m) used for BOTH u=rint(255p) and l += p
// (per-lane accumulation, one 16-lane shfl reduce at the end). l is summed with
// the final m directly — same as the JAX reference's softmax; old online-rescale
// l differed only in last-ulp fp32 rounding.
__global__ __launch_bounds__(256, 2) void k_attn(const u16* __restrict__ Qq,
                                                 const u16* __restrict__ Kq,
                                                 const u16* __restrict__ Vt,
                                                 u16* __restrict__ O) {
  __shared__ u16 Ks[2][64 * 128];  // dbuf, swizzle g^(tok&15), 32KB
  __shared__ u16 Vs[2][128 * 64];  // dbuf, swizzle g^(d&7),   32KB
  __shared__ u16 Ub[4 * 32 * 64];  // per-wave u tile, swizzle g^(q&7), 16KB

  const int h = blockIdx.y;
  const int r0 = blockIdx.x * 128;
  const int t = threadIdx.x;
  const int w = t >> 6, lane = t & 63, quad = lane >> 4, l16 = lane & 15;

  const u16* Qh = Qq + (size_t)(r0 + w * 32) * CDIM + h * HDIM;
  const u16* Kh = Kq + h * HDIM;
  const u16* Vh = Vt + (size_t)h * HDIM * NKV;

  bf16x8 qf[2][4];
#pragma unroll
  for (int ti = 0; ti < 2; ++ti)
#pragma unroll
    for (int ks = 0; ks < 4; ++ks)
      qf[ti][ks] = *(const bf16x8*)&Qh[(size_t)(ti * 16 + l16) * CDIM + ks * 32 + quad * 8];

  const int ktl = (w * 4) * 4 + (lane >> 4);
  const int kg = (lane & 15);
  const int vdl = (w * 4) * 8 + (lane >> 3);
  const int vg = (lane & 7);

#define STAGE_K(ck, b) { \
    _Pragma("unroll") for (int j = 0; j < 4; ++j) { \
      int tok = ktl + j * 4; \
      GLOAD_LDS16(Kh + (size_t)((ck) * 64 + tok) * CDIM + (kg ^ (tok & 15)) * 8, \
                  &Ks[b][(w * 4 + j) * 512]); \
    } }
#define STAGE_V(ck, b) { \
    _Pragma("unroll") for (int j = 0; j < 4; ++j) { \
      int dl = vdl + j * 8; \
      GLOAD_LDS16(Vh + (size_t)dl * NKV + (ck) * 64 + (vg ^ (dl & 7)) * 8, \
                  &Vs[b][(w * 4 + j) * 512]); \
    } }

  // ================= phase 1: row max m only =================
  float m[8];
#pragma unroll
  for (int i = 0; i < 8; ++i) m[i] = -3e38f;

  STAGE_K(0, 0);
  for (int ck = 0; ck < 16; ++ck) {
    const int cur = ck & 1;
    if (ck + 1 < 16) { STAGE_K(ck + 1, cur ^ 1); VMCNT(4); }
    else             { VMCNT(0); }
    BARRIER();

    f32x4 s_acc[2][4];
#pragma unroll
    for (int ti = 0; ti < 2; ++ti)
#pragma unroll
      for (int tj = 0; tj < 4; ++tj) s_acc[ti][tj] = (f32x4){0.f, 0.f, 0.f, 0.f};
    __builtin_amdgcn_s_setprio(1);
#pragma unroll
    for (int ks = 0; ks < 4; ++ks)
#pragma unroll
      for (int tj = 0; tj < 4; ++tj) {
        bf16x8 bk = *(const bf16x8*)&Ks[cur][(tj * 16 + l16) * 128 + (((ks * 4 + quad) ^ l16) << 3)];
        s_acc[0][tj] = __builtin_amdgcn_mfma_f32_16x16x32_bf16(qf[0][ks], bk, s_acc[0][tj], 0, 0, 0);
        s_acc[1][tj] = __builtin_amdgcn_mfma_f32_16x16x32_bf16(qf[1][ks], bk, s_acc[1][tj], 0, 0, 0);
      }
    __builtin_amdgcn_s_setprio(0);

#pragma unroll
    for (int ti = 0; ti < 2; ++ti) {
      float cm[4];
#pragma unroll
      for (int r = 0; r < 4; ++r)
        cm[r] = fmaxf(fmaxf(s_acc[ti][0][r], s_acc[ti][1][r]),
                      fmaxf(s_acc[ti][2][r], s_acc[ti][3][r]));
#pragma unroll
      for (int off = 1; off < 16; off <<= 1)
#pragma unroll
        for (int r = 0; r < 4; ++r) cm[r] = fmaxf(cm[r], __shfl_xor(cm[r], off));
#pragma unroll
      for (int r = 0; r < 4; ++r) m[ti*4 + r] = fmaxf(m[ti*4 + r], cm[r]);
    }
    BARRIER();   // protect Ks[cur] before next stage overwrites it
  }

  // ================= phase 2: QK^T recompute, p -> (u, l), PV =================
  float lsum[8];
#pragma unroll
  for (int i = 0; i < 8; ++i) lsum[i] = 0.f;

  f32x4 o_acc[2][8];
#pragma unroll
  for (int ti = 0; ti < 2; ++ti)
#pragma unroll
    for (int tj = 0; tj < 8; ++tj) o_acc[ti][tj] = (f32x4){0.f, 0.f, 0.f, 0.f};

  STAGE_K(0, 0); STAGE_V(0, 0);
  for (int ck = 0; ck < 16; ++ck) {
    const int cur = ck & 1;
    if (ck + 1 < 16) { STAGE_K(ck + 1, cur ^ 1); STAGE_V(ck + 1, cur ^ 1); VMCNT(8); }
    else             { VMCNT(0); }
    BARRIER();

    f32x4 s_acc[2][4];
#pragma unroll
    for (int ti = 0; ti < 2; ++ti)
#pragma unroll
      for (int tj = 0; tj < 4; ++tj) s_acc[ti][tj] = (f32x4){0.f, 0.f, 0.f, 0.f};
    __builtin_amdgcn_s_setprio(1);
#pragma unroll
    for (int ks = 0; ks < 4; ++ks)
#pragma unroll
      for (int tj = 0; tj < 4; ++tj) {
        bf16x8 bk = *(const bf16x8*)&Ks[cur][(tj * 16 + l16) * 128 + (((ks * 4 + quad) ^ l16) << 3)];
        s_acc[0][tj] = __builtin_amdgcn_mfma_f32_16x16x32_bf16(qf[0][ks], bk, s_acc[0][tj], 0, 0, 0);
        s_acc[1][tj] = __builtin_amdgcn_mfma_f32_16x16x32_bf16(qf[1][ks], bk, s_acc[1][tj], 0, 0, 0);
      }
    __builtin_amdgcn_s_setprio(0);

#pragma unroll
    for (int ti = 0; ti < 2; ++ti)
#pragma unroll
      for (int tj = 0; tj < 4; ++tj)
#pragma unroll
        for (int r = 0; r < 4; ++r) {
          int ql = ti * 16 + quad * 4 + r;
          int tok = tj * 16 + l16;
          float p = __expf(s_acc[ti][tj][r] - m[ti*4 + r]);
          lsum[ti*4 + r] += p;
          float u = rintf(255.f * p);
          Ub[w * 2048 + ql * 64 + ((((tok >> 3) ^ (ql & 7)) << 3) | (tok & 7))] = f2bf(u);
        }
#pragma unroll
    for (int ks2 = 0; ks2 < 2; ++ks2) {
      bf16x8 au[2];
#pragma unroll
      for (int ti = 0; ti < 2; ++ti) {
        int ql = ti * 16 + l16;
        au[ti] = *(const bf16x8*)&Ub[w * 2048 + ql * 64 + (((ks2 * 4 + quad) ^ (l16 & 7)) << 3)];
      }
      __builtin_amdgcn_s_setprio(1);
#pragma unroll
      for (int tj = 0; tj < 8; ++tj) {
        bf16x8 bv = *(const bf16x8*)&Vs[cur][(tj * 16 + l16) * 64 + (((ks2 * 4 + quad) ^ (l16 & 7)) << 3)];
        o_acc[0][tj] = __builtin_amdgcn_mfma_f32_16x16x32_bf16(au[0], bv, o_acc[0][tj], 0, 0, 0);
        o_acc[1][tj] = __builtin_amdgcn_mfma_f32_16x16x32_bf16(au[1], bv, o_acc[1][tj], 0, 0, 0);
      }
      __builtin_amdgcn_s_setprio(0);
    }
    BARRIER();   // protect Ks/Vs[cur] before next stage overwrites it
  }
#undef STAGE_K
#undef STAGE_V

  // final row-sum reduce across the 16 token-lanes, then 1/(255*l)
#pragma unroll
  for (int off = 1; off < 16; off <<= 1)
#pragma unroll
    for (int i = 0; i < 8; ++i) lsum[i] += __shfl_xor(lsum[i], off);
  float rinv[8];
#pragma unroll
  for (int i = 0; i < 8; ++i) rinv[i] = 1.f / (255.f * lsum[i]);

#pragma unroll
  for (int ti = 0; ti < 2; ++ti)
#pragma unroll
    for (int tj = 0; tj < 8; ++tj)
#pragma unroll
      for (int r = 0; r < 4; ++r) {
        int row = r0 + w * 32 + ti * 16 + quad * 4 + r;
        int d = tj * 16 + l16;
        O[(size_t)row * CDIM + h * HDIM + d] = f2bf(o_acc[ti][tj][r] * rinv[ti*4 + r]);
      }
}

extern "C" void kernel_launch(void* const* d_in, const int* in_sizes, int n_in,
                              void* d_out, int out_size, void* d_ws, size_t ws_size,
                              hipStream_t stream) {
  const float* x    = (const float*)d_in[0];
  const float* cond = (const float*)d_in[1];
  const float* Wq   = (const float*)d_in[2];
  const float* bq   = (const float*)d_in[3];
  const float* Wkv  = (const float*)d_in[4];
  const float* bkv  = (const float*)d_in[5];
  const float* Wp   = (const float*)d_in[6];
  const float* bp   = (const float*)d_in[7];
  float* out = (float*)d_out;

  char* ws = (char*)d_ws;
  size_t off = 0;
  auto alloc = [&](size_t bytes) -> char* {
    char* p = ws + off;
    off += (bytes + 255) & ~(size_t)255;
    return p;
  };
  u16*   Xb    = (u16*)alloc((size_t)NQ * CDIM * 2);
  u16*   Cb    = (u16*)alloc((size_t)NKV * CDIM * 2);
  u16*   WqT   = (u16*)alloc((size_t)CDIM * CDIM * 2);
  u16*   WkvT  = (u16*)alloc((size_t)2 * CDIM * CDIM * 2);
  float* KVraw = (float*)alloc((size_t)NKV * 2 * CDIM * 4);  // only V-half written
  u16*   Qq    = (u16*)alloc((size_t)NQ * CDIM * 2);
  u16*   Kq    = (u16*)alloc((size_t)NKV * CDIM * 2);
  u16*   Vt    = (u16*)alloc((size_t)CDIM * NKV * 2);
  float* vmax  = (float*)alloc((size_t)CDIM * 4);
  u16*   Ob    = (u16*)alloc((size_t)NQ * CDIM * 2);
  u16*   WpT   = (u16*)alloc((size_t)CDIM * CDIM * 2);

  k_prep<<<22536, 256, 0, stream>>>(x, cond, Wq, Wkv, Xb, Cb, WqT, WkvT, (u32*)vmax);
  k_gemm_qkv<<<256, 512, 0, stream>>>(Xb, Cb, WqT, WkvT, Wp, bq, bkv, Qq, Kq, KVraw,
                                      WpT, (u32*)vmax);
  k_vt_quant<<<dim3(CDIM/32, NKV/32), 256, 0, stream>>>(KVraw + CDIM, vmax, Vt);
  k_attn<<<dim3(NQ/128, NHEADS), 256, 0, stream>>>(Qq, Kq, Vt, Ob);
  k_gemm_bt<<<dim3(CDIM/256, NQ/128), 512, 0, stream>>>(Ob, WpT, bp, out, CDIM, CDIM);
}

// Round 10
// 328.106 us; speedup vs baseline: 1.0835x; 1.0333x over previous
//
#include <hip/hip_runtime.h>

typedef unsigned short u16;
typedef unsigned int u32;
typedef __attribute__((ext_vector_type(8))) short bf16x8;
typedef __attribute__((ext_vector_type(4))) float f32x4;

#define NQ 4096      // B*N query tokens
#define NKV 1024     // B*M kv tokens
#define CDIM 2048
#define NHEADS 16
#define HDIM 128
#define QSCALE 0.08838834764831843f  // 1/sqrt(128)

#define GLOAD_LDS16(g, l) __builtin_amdgcn_global_load_lds( \
    (const __attribute__((address_space(1))) unsigned int*)(g), \
    (__attribute__((address_space(3))) unsigned int*)(l), 16, 0, 0)

#define BARRIER() __builtin_amdgcn_s_barrier()
#define VMCNT(n) asm volatile("s_waitcnt vmcnt(" #n ")" ::: "memory")
#define LGKM0() asm volatile("s_waitcnt lgkmcnt(0)" ::: "memory")

__device__ __forceinline__ u16 f2bf(float f) {
  union { float f; u32 u; } a; a.f = f;
  u32 r = (a.u + 0x7fffu + ((a.u >> 16) & 1u)) >> 16;   // RNE
  return (u16)r;
}

// ---------------- fused prep: convert x/cond to bf16, transpose Wq/Wkv, zero vmax --
__global__ __launch_bounds__(256) void k_prep(const float* __restrict__ x,
                                              const float* __restrict__ cond,
                                              const float* __restrict__ Wq,
                                              const float* __restrict__ Wkv,
                                              u16* __restrict__ Xb,
                                              u16* __restrict__ Cb,
                                              u16* __restrict__ WqT,
                                              u16* __restrict__ WkvT,
                                              u32* __restrict__ vmax) {
  __shared__ float tile[32][33];
  const int id = blockIdx.x;
  if (id < 10240) {
    const int nx = NQ * CDIM / 4;
    int i = id * 256 + threadIdx.x;
    const float* in; u16* out; int j;
    if (i < nx) { in = x; out = Xb; j = i; }
    else        { in = cond; out = Cb; j = i - nx; }
    float4 v = ((const float4*)in)[j];
    uint2 r;
    r.x = (u32)f2bf(v.x) | ((u32)f2bf(v.y) << 16);
    r.y = (u32)f2bf(v.z) | ((u32)f2bf(v.w) << 16);
    ((uint2*)out)[j] = r;
    return;
  }
  if (id >= 22528) {
    int i = (id - 22528) * 256 + threadIdx.x;
    if (i < CDIM) vmax[i] = 0u;
    return;
  }
  int id2 = id - 10240;
  const float* in; u16* out; int R, Ccols, bx, by;
  if (id2 < 4096) { in = Wq;  out = WqT;  R = 2048; Ccols = 2048; bx = id2 & 63;  by = id2 >> 6; }
  else            { int i = id2 - 4096; in = Wkv; out = WkvT; R = 2048; Ccols = 4096; bx = i & 127; by = i >> 7; }
  int c0 = bx * 32, r0 = by * 32;
  int tx = threadIdx.x & 31, ty = threadIdx.x >> 5;
#pragma unroll
  for (int i = 0; i < 4; ++i)
    tile[ty + i*8][tx] = in[(size_t)(r0 + ty + i*8) * Ccols + c0 + tx];
  __syncthreads();
#pragma unroll
  for (int i = 0; i < 4; ++i)
    out[(size_t)(c0 + ty + i*8) * R + r0 + tx] = f2bf(tile[tx][ty + i*8]);
}

// ======================================================================
// 256x256-tile, BK=64, 8-wave, 4-phase/K-tile bf16 GEMM core (R3-proven).
// XOR-swizzled LDS via pre-swizzled global source; counted vmcnt(4) at
// tile boundary (never 0 in steady state). Bit-identical MFMA K-order.
// ======================================================================
__device__ __forceinline__ void gemm256_core(const u16* __restrict__ Ap,
                                             const u16* __restrict__ Bp,
                                             int lda, int ldb, int NT,
                                             u16* __restrict__ la0, u16* __restrict__ la1,
                                             u16* __restrict__ lb0, u16* __restrict__ lb1,
                                             f32x4 (&acc)[8][4]) {
  const int tid = threadIdx.x;
  const int lane = tid & 63, w = tid >> 6, quad = lane >> 4, l16 = lane & 15;
  const int wr = w >> 2, wc = w & 3;
  const int xo = (l16 & 7) << 4;                 // ds_read byte XOR
  const int rA = tid >> 3;                       // staging row 0..63 within half
  const int cbu = ((((tid & 7) << 4) ^ ((rA & 7) << 4)) >> 1);  // pre-swizzled src col (u16)

  bf16x8 a[4][2];
  bf16x8 bb[2][2][2];

#define STAGE(P, ld, L, h, tt) do { \
    const u16* g0_ = (P) + (size_t)((h) * 128 + rA) * (ld) + (size_t)(tt) * 64 + cbu; \
    u16* l0_ = (L) + (h) * 8192 + w * 512; \
    GLOAD_LDS16(g0_, l0_); \
    GLOAD_LDS16(g0_ + (size_t)64 * (ld), l0_ + 4096); \
  } while (0)

#define RD_A(bufp, mh) { \
    _Pragma("unroll") for (int rf = 0; rf < 4; ++rf) \
      _Pragma("unroll") for (int ks = 0; ks < 2; ++ks) \
        a[rf][ks] = *(const bf16x8*)((const char*)(bufp) + \
          (size_t)(wr * 128 + (mh) * 64 + rf * 16 + l16) * 128 + ((ks * 64 + quad * 16) ^ xo)); }

#define RD_B(bufp, nh) { \
    _Pragma("unroll") for (int cf = 0; cf < 2; ++cf) \
      _Pragma("unroll") for (int ks = 0; ks < 2; ++ks) \
        bb[nh][cf][ks] = *(const bf16x8*)((const char*)(bufp) + \
          (size_t)(wc * 64 + (nh) * 32 + cf * 16 + l16) * 128 + ((ks * 64 + quad * 16) ^ xo)); }

#define MQ(mh, nh) { \
    __builtin_amdgcn_s_setprio(1); \
    _Pragma("unroll") for (int rf = 0; rf < 4; ++rf) \
      _Pragma("unroll") for (int cf = 0; cf < 2; ++cf) \
        _Pragma("unroll") for (int ks = 0; ks < 2; ++ks) \
          acc[(mh)*4+rf][(nh)*2+cf] = __builtin_amdgcn_mfma_f32_16x16x32_bf16( \
            a[rf][ks], bb[nh][cf][ks], acc[(mh)*4+rf][(nh)*2+cf], 0, 0, 0); \
    __builtin_amdgcn_s_setprio(0); }

  STAGE(Bp, ldb, lb0, 0, 0);
  STAGE(Bp, ldb, lb0, 1, 0);
  STAGE(Ap, lda, la0, 0, 0);
  STAGE(Ap, lda, la0, 1, 0);
  STAGE(Bp, ldb, lb1, 0, 1);
  STAGE(Bp, ldb, lb1, 1, 1);
  VMCNT(4);
  BARRIER();

  for (int t = 0; t < NT; ++t) {
    u16* Ab = (t & 1) ? la1 : la0;
    u16* Bb = (t & 1) ? lb1 : lb0;
    u16* An = (t & 1) ? la0 : la1;
    const bool s1 = (t + 1) < NT, s2 = (t + 2) < NT;
    // ph0
    RD_A(Ab, 0); RD_B(Bb, 0);
    if (s1) STAGE(Ap, lda, An, 0, t + 1);
    BARRIER(); LGKM0();
    MQ(0, 0);
    BARRIER();
    // ph1
    RD_B(Bb, 1);
    if (s1) STAGE(Ap, lda, An, 1, t + 1);
    BARRIER(); LGKM0();
    MQ(0, 1);
    BARRIER();
    // ph2
    RD_A(Ab, 1);
    if (s2) STAGE(Bp, ldb, Bb, 0, t + 2);
    BARRIER(); LGKM0();
    MQ(1, 1);
    BARRIER();
    // ph3
    if (s2) STAGE(Bp, ldb, Bb, 1, t + 2);
    MQ(1, 0);
    if (s2) { VMCNT(4); } else { VMCNT(0); }
    BARRIER();
  }
  VMCNT(0);
#undef STAGE
#undef RD_A
#undef RD_B
#undef MQ
}

// ---------------- bf16 MFMA GEMM (out-proj), BM=128 x BN=256, full K, direct out --
__global__ __launch_bounds__(512, 2) void k_gemm_bt(const u16* __restrict__ A,
                                                    const u16* __restrict__ Bt,
                                                    const float* __restrict__ bias,
                                                    float* __restrict__ Cout,
                                                    int Ndim, int Kdim) {
  __shared__ u16 la0[8192];
  __shared__ u16 la1[8192];
  __shared__ u16 lb0[16384];
  __shared__ u16 lb1[16384];
  const int bn = blockIdx.x, bm = blockIdx.y;
  const int tid = threadIdx.x;
  const int lane = tid & 63, w = tid >> 6, quad = lane >> 4, l16 = lane & 15;
  const int wr = w >> 2, wc = w & 3;
  const int xo = (l16 & 7) << 4;
  const int rA = tid >> 3;
  const int cbu = ((((tid & 7) << 4) ^ ((rA & 7) << 4)) >> 1);

  const u16* Ap = A + (size_t)bm * 128 * Kdim;
  const u16* Bp = Bt + (size_t)bn * 256 * Kdim;
  const int NT = Kdim >> 6;

  f32x4 acc[4][4];
#pragma unroll
  for (int i = 0; i < 4; ++i)
#pragma unroll
    for (int j = 0; j < 4; ++j) acc[i][j] = (f32x4){0.f, 0.f, 0.f, 0.f};

  bf16x8 a[4][2];
  bf16x8 bb[2][2][2];

#define STAGE_A(L, tt) do { \
    const u16* g0_ = Ap + (size_t)rA * Kdim + (size_t)(tt) * 64 + cbu; \
    u16* l0_ = (L) + w * 512; \
    GLOAD_LDS16(g0_, l0_); \
    GLOAD_LDS16(g0_ + (size_t)64 * Kdim, l0_ + 4096); \
  } while (0)

#define STAGE_B(L, h, tt) do { \
    const u16* g0_ = Bp + (size_t)((h) * 128 + rA) * Kdim + (size_t)(tt) * 64 + cbu; \
    u16* l0_ = (L) + (h) * 8192 + w * 512; \
    GLOAD_LDS16(g0_, l0_); \
    GLOAD_LDS16(g0_ + (size_t)64 * Kdim, l0_ + 4096); \
  } while (0)

#define RD_A2(bufp) { \
    _Pragma("unroll") for (int rf = 0; rf < 4; ++rf) \
      _Pragma("unroll") for (int ks = 0; ks < 2; ++ks) \
        a[rf][ks] = *(const bf16x8*)((const char*)(bufp) + \
          (size_t)(wr * 64 + rf * 16 + l16) * 128 + ((ks * 64 + quad * 16) ^ xo)); }

#define RD_B2(bufp, nh) { \
    _Pragma("unroll") for (int cf = 0; cf < 2; ++cf) \
      _Pragma("unroll") for (int ks = 0; ks < 2; ++ks) \
        bb[nh][cf][ks] = *(const bf16x8*)((const char*)(bufp) + \
          (size_t)(wc * 64 + (nh) * 32 + cf * 16 + l16) * 128 + ((ks * 64 + quad * 16) ^ xo)); }

#define MQ2(nh) { \
    __builtin_amdgcn_s_setprio(1); \
    _Pragma("unroll") for (int rf = 0; rf < 4; ++rf) \
      _Pragma("unroll") for (int cf = 0; cf < 2; ++cf) \
        _Pragma("unroll") for (int ks = 0; ks < 2; ++ks) \
          acc[rf][(nh)*2+cf] = __builtin_amdgcn_mfma_f32_16x16x32_bf16( \
            a[rf][ks], bb[nh][cf][ks], acc[rf][(nh)*2+cf], 0, 0, 0); \
    __builtin_amdgcn_s_setprio(0); }

  STAGE_A(la0, 0);
  STAGE_B(lb0, 0, 0);
  STAGE_B(lb0, 1, 0);
  STAGE_B(lb1, 0, 1);
  STAGE_B(lb1, 1, 1);
  VMCNT(4);
  BARRIER();

  for (int t = 0; t < NT; ++t) {
    u16* Ab = (t & 1) ? la1 : la0;
    u16* Bb = (t & 1) ? lb1 : lb0;
    u16* An = (t & 1) ? la0 : la1;
    const bool s1 = (t + 1) < NT, s2 = (t + 2) < NT;
    // ph0: read A(all) + B(nh0); stage A(t+1) -> other A buf; MFMA nh0
    RD_A2(Ab); RD_B2(Bb, 0);
    if (s1) STAGE_A(An, t + 1);
    BARRIER(); LGKM0();
    MQ2(0);
    BARRIER();
    // ph1: read B(nh1); all waves' Bb reads retired -> stage B(t+2) into Bb
    RD_B2(Bb, 1);
    LGKM0();
    BARRIER();
    if (s2) { STAGE_B(Bb, 0, t + 2); STAGE_B(Bb, 1, t + 2); }
    MQ2(1);
    if (s2) { VMCNT(4); } else { VMCNT(0); }
    BARRIER();
  }
  VMCNT(0);
#undef STAGE_A
#undef STAGE_B
#undef RD_A2
#undef RD_B2
#undef MQ2

#pragma unroll
  for (int mf = 0; mf < 4; ++mf) {
    int row = bm * 128 + wr * 64 + mf * 16 + quad * 4;
#pragma unroll
    for (int nf = 0; nf < 4; ++nf) {
      int col = bn * 256 + wc * 64 + nf * 16 + l16;
      float bv = bias[col];
#pragma unroll
      for (int r = 0; r < 4; ++r)
        Cout[(size_t)(row + r) * Ndim + col] = acc[mf][nf][r] + bv;
    }
  }
}

// ---------------- fused QKV projection GEMM + quant epilogue + V colmax + Wp filler --
__global__ __launch_bounds__(512, 2) void k_gemm_qkv(const u16* __restrict__ Xb,
                                                     const u16* __restrict__ Cb,
                                                     const u16* __restrict__ WqT,
                                                     const u16* __restrict__ WkvT,
                                                     const float* __restrict__ Wp,
                                                     const float* __restrict__ bq,
                                                     const float* __restrict__ bkv,
                                                     u16* __restrict__ Qq,
                                                     u16* __restrict__ Kq,
                                                     float* __restrict__ Vraw,
                                                     u16* __restrict__ WpT,
                                                     u32* __restrict__ vmax) {
  __shared__ u16 la0[16384];
  __shared__ u16 la1[16384];
  __shared__ u16 lb0[16384];
  __shared__ u16 lb1[16384];

  const int id = blockIdx.x;
  const int tid = threadIdx.x;

  if (id >= 192) {
    // ---- Wp transpose filler: 64 blocks x 16 tiles of 64x64 (73-pad: no conflicts) --
    int fid = id - 192;
    float (*ft)[73] = (float(*)[73])la0;   // 64x73 fp32 = 18.7KB, aliases GEMM LDS
    const int rr = tid >> 3, cb = (tid & 7) * 8;
    for (int i = 0; i < 16; ++i) {
      int tIdx = fid * 16 + i;
      int r0 = (tIdx >> 5) * 64, c0 = (tIdx & 31) * 64;
      __syncthreads();
#pragma unroll
      for (int j = 0; j < 2; ++j)
        *(float4*)&ft[rr][cb + j * 4] =
            *(const float4*)&Wp[(size_t)(r0 + rr) * 2048 + c0 + cb + j * 4];
      __syncthreads();
      u16 tmp[8];
#pragma unroll
      for (int j = 0; j < 8; ++j) tmp[j] = f2bf(ft[cb + j][rr]);
      *(uint4*)&WpT[(size_t)(c0 + rr) * 2048 + r0 + cb] = *(uint4*)tmp;
    }
    return;
  }

  const u16 *Ain; const u16 *Bt; const float* bias;
  u16* out16 = nullptr; float* outf = nullptr;
  int bm, bn, ostride, ocol;
  float premul = 1.0f;
  if (id < 128) {
    bm = id >> 3; bn = id & 7;
    Ain = Xb; Bt = WqT + (size_t)(bn * 256) * CDIM;
    bias = bq + bn * 256; out16 = Qq; ostride = CDIM; ocol = bn * 256;
    premul = QSCALE;
  } else if (id < 160) {
    int i2 = id - 128; bm = i2 >> 3; bn = i2 & 7;
    Ain = Cb; Bt = WkvT + (size_t)(bn * 256) * CDIM;
    bias = bkv + bn * 256; out16 = Kq; ostride = CDIM; ocol = bn * 256;
  } else {
    int i3 = id - 160; bm = i3 >> 3; bn = i3 & 7;
    Ain = Cb; Bt = WkvT + (size_t)(2048 + bn * 256) * CDIM;
    bias = bkv + 2048 + bn * 256; outf = Vraw; ostride = 2 * CDIM; ocol = 2048 + bn * 256;
  }

  f32x4 acc[8][4];
#pragma unroll
  for (int i = 0; i < 8; ++i)
#pragma unroll
    for (int j = 0; j < 4; ++j) acc[i][j] = (f32x4){0.f, 0.f, 0.f, 0.f};

  gemm256_core(Ain + (size_t)bm * 256 * CDIM, Bt, CDIM, CDIM, CDIM >> 6,
               la0, la1, lb0, lb1, acc);

  const int w = tid >> 6, lane = tid & 63, quad = lane >> 4, l16 = lane & 15;
  const int wr = w >> 2, wc = w & 3;

  float bv[4];
#pragma unroll
  for (int nf = 0; nf < 4; ++nf) bv[nf] = bias[wc * 64 + nf * 16 + l16];

  if (outf) {
    float cmax[4];
#pragma unroll
    for (int nf = 0; nf < 4; ++nf) cmax[nf] = 0.f;
#pragma unroll
    for (int mf = 0; mf < 8; ++mf) {
      int row = bm * 256 + wr * 128 + mf * 16 + quad * 4;
#pragma unroll
      for (int nf = 0; nf < 4; ++nf) {
        int col = ocol + wc * 64 + nf * 16 + l16;
#pragma unroll
        for (int r = 0; r < 4; ++r) {
          float v = acc[mf][nf][r] + bv[nf];
          outf[(size_t)(row + r) * ostride + col] = v;
          cmax[nf] = fmaxf(cmax[nf], fabsf(v));
        }
      }
    }
#pragma unroll
    for (int nf = 0; nf < 4; ++nf) {
      cmax[nf] = fmaxf(cmax[nf], __shfl_xor(cmax[nf], 16));
      cmax[nf] = fmaxf(cmax[nf], __shfl_xor(cmax[nf], 32));
    }
    if (quad == 0) {
#pragma unroll
      for (int nf = 0; nf < 4; ++nf)
        atomicMax(&vmax[(ocol - 2048) + wc * 64 + nf * 16 + l16],
                  __float_as_uint(cmax[nf]));
    }
    return;
  }

  // Q/K: fused per-row-128 symmetric int8 fake-quant
  float amax[8][4];
#pragma unroll
  for (int mf = 0; mf < 8; ++mf)
#pragma unroll
    for (int r = 0; r < 4; ++r) amax[mf][r] = 0.f;
#pragma unroll
  for (int mf = 0; mf < 8; ++mf)
#pragma unroll
    for (int nf = 0; nf < 4; ++nf)
#pragma unroll
      for (int r = 0; r < 4; ++r) {
        float v = (acc[mf][nf][r] + bv[nf]) * premul;
        acc[mf][nf][r] = v;
        amax[mf][r] = fmaxf(amax[mf][r], fabsf(v));
      }
#pragma unroll
  for (int off = 1; off < 16; off <<= 1)
#pragma unroll
    for (int mf = 0; mf < 8; ++mf)
#pragma unroll
      for (int r = 0; r < 4; ++r)
        amax[mf][r] = fmaxf(amax[mf][r], __shfl_xor(amax[mf][r], off));

  float (*rmax)[256] = (float(*)[256])(&la0[0]);
  if (l16 == 0)
#pragma unroll
    for (int mf = 0; mf < 8; ++mf)
#pragma unroll
      for (int r = 0; r < 4; ++r)
        rmax[wc][wr * 128 + mf * 16 + quad * 4 + r] = amax[mf][r];
  __syncthreads();

  const int g2 = (wc >> 1) << 1;
#pragma unroll
  for (int mf = 0; mf < 8; ++mf) {
    int rowl = wr * 128 + mf * 16 + quad * 4;
    int row = bm * 256 + rowl;
#pragma unroll
    for (int r = 0; r < 4; ++r) {
      float s = fmaxf(fmaxf(rmax[g2][rowl + r], rmax[g2 + 1][rowl + r]) * (1.f / 127.f), 1e-8f);
#pragma unroll
      for (int nf = 0; nf < 4; ++nf) {
        int col = ocol + wc * 64 + nf * 16 + l16;
        float q = fminf(fmaxf(rintf(acc[mf][nf][r] / s), -127.f), 127.f) * s;
        out16[(size_t)(row + r) * ostride + col] = f2bf(q);
      }
    }
  }
}

// ---------------- quantize V and write transposed: Vt[(h*128+d)][token] ----------------
__global__ __launch_bounds__(256) void k_vt_quant(const float* __restrict__ in,
                                                  const float* __restrict__ vmax,
                                                  u16* __restrict__ Vt) {
  __shared__ float tile[32][33];
  int c0 = blockIdx.x * 32;
  int t0 = blockIdx.y * 32;
  int tx = threadIdx.x & 31, ty = threadIdx.x >> 5;
#pragma unroll
  for (int i = 0; i < 4; ++i)
    tile[ty + i*8][tx] = in[(size_t)(t0 + ty + i*8) * 4096 + c0 + tx];
  __syncthreads();
#pragma unroll
  for (int i = 0; i < 4; ++i) {
    int d = ty + i*8;
    float s = fmaxf(vmax[c0 + d] * (1.f / 127.f), 1e-8f);
    float q = fminf(fmaxf(rintf(tile[tx][d] / s), -127.f), 127.f) * s;
    Vt[(size_t)(c0 + d) * 1024 + t0 + tx] = f2bf(q);
  }
}

// ---------------- merged attention, phase-1-lite @ KVBLK=128 ----------------------
// phase1: QK^T -> row max m ONLY, at 128 tokens/chunk: V unused in phase 1, so
// Ks[b]+Vs[b] together form one 32KB K-buffer (tokens 0-63 in Ks[b], 64-127 in
// Vs[b]). 8 chunks instead of 16 -> half the barriers/vmcnt waits; one combined
// shfl-fmax reduce per 128 tokens (fmax order-invariant -> m bit-identical).
// phase2: QK^T recompute; p = exp(s-m) feeds BOTH u=rint(255p) and l += p.
// u is an integer in [0,255] -> exactly representable in bf16 -> bare >>16.
__global__ __launch_bounds__(256, 2) void k_attn(const u16* __restrict__ Qq,
                                                 const u16* __restrict__ Kq,
                                                 const u16* __restrict__ Vt,
                                                 u16* __restrict__ O) {
  __shared__ u16 Ks[2][64 * 128];  // dbuf, swizzle g^(tok&15), 32KB
  __shared__ u16 Vs[2][128 * 64];  // dbuf, swizzle g^(d&7),   32KB  (phase1: K half2)
  __shared__ u16 Ub[4 * 32 * 64];  // per-wave u tile, swizzle g^(q&7), 16KB

  const int h = blockIdx.y;
  const int r0 = blockIdx.x * 128;
  const int t = threadIdx.x;
  const int w = t >> 6, lane = t & 63, quad = lane >> 4, l16 = lane & 15;

  const u16* Qh = Qq + (size_t)(r0 + w * 32) * CDIM + h * HDIM;
  const u16* Kh = Kq + h * HDIM;
  const u16* Vh = Vt + (size_t)h * HDIM * NKV;

  bf16x8 qf[2][4];
#pragma unroll
  for (int ti = 0; ti < 2; ++ti)
#pragma unroll
    for (int ks = 0; ks < 4; ++ks)
      qf[ti][ks] = *(const bf16x8*)&Qh[(size_t)(ti * 16 + l16) * CDIM + ks * 32 + quad * 8];

  const int ktl = (w * 4) * 4 + (lane >> 4);
  const int kg = (lane & 15);
  const int vdl = (w * 4) * 8 + (lane >> 3);
  const int vg = (lane & 7);

// stage one 64-token K chunk (ck in 64-token units) into buffer buf (u16*)
#define STAGE_K_TO(ck, bufp) { \
    _Pragma("unroll") for (int j = 0; j < 4; ++j) { \
      int tok = ktl + j * 4; \
      GLOAD_LDS16(Kh + (size_t)((ck) * 64 + tok) * CDIM + (kg ^ (tok & 15)) * 8, \
                  (bufp) + (w * 4 + j) * 512); \
    } }
#define STAGE_V(ck, b) { \
    _Pragma("unroll") for (int j = 0; j < 4; ++j) { \
      int dl = vdl + j * 8; \
      GLOAD_LDS16(Vh + (size_t)dl * NKV + (ck) * 64 + (vg ^ (dl & 7)) * 8, \
                  &Vs[b][(w * 4 + j) * 512]); \
    } }
// phase-1 pair stage: 128 tokens (chunk c8 in 128-token units) -> Ks[b] + Vs[b]
#define STAGE_K2(c8, b) { STAGE_K_TO((c8) * 2, &Ks[b][0]); STAGE_K_TO((c8) * 2 + 1, &Vs[b][0]); }

  // ================= phase 1: row max m only, 8 chunks of 128 tokens ============
  float m[8];
#pragma unroll
  for (int i = 0; i < 8; ++i) m[i] = -3e38f;

  STAGE_K2(0, 0);
  for (int c8 = 0; c8 < 8; ++c8) {
    const int cur = c8 & 1;
    if (c8 + 1 < 8) { STAGE_K2(c8 + 1, cur ^ 1); VMCNT(16); }
    else            { VMCNT(0); }
    BARRIER();

    float cm[2][4];
#pragma unroll
    for (int ti = 0; ti < 2; ++ti)
#pragma unroll
      for (int r = 0; r < 4; ++r) cm[ti][r] = -3e38f;

#pragma unroll
    for (int hf = 0; hf < 2; ++hf) {
      const u16* Kbuf = hf ? &Vs[cur][0] : &Ks[cur][0];
      f32x4 s_acc[2][4];
#pragma unroll
      for (int ti = 0; ti < 2; ++ti)
#pragma unroll
        for (int tj = 0; tj < 4; ++tj) s_acc[ti][tj] = (f32x4){0.f, 0.f, 0.f, 0.f};
      __builtin_amdgcn_s_setprio(1);
#pragma unroll
      for (int ks = 0; ks < 4; ++ks)
#pragma unroll
        for (int tj = 0; tj < 4; ++tj) {
          bf16x8 bk = *(const bf16x8*)&Kbuf[(tj * 16 + l16) * 128 + (((ks * 4 + quad) ^ l16) << 3)];
          s_acc[0][tj] = __builtin_amdgcn_mfma_f32_16x16x32_bf16(qf[0][ks], bk, s_acc[0][tj], 0, 0, 0);
          s_acc[1][tj] = __builtin_amdgcn_mfma_f32_16x16x32_bf16(qf[1][ks], bk, s_acc[1][tj], 0, 0, 0);
        }
      __builtin_amdgcn_s_setprio(0);
#pragma unroll
      for (int ti = 0; ti < 2; ++ti)
#pragma unroll
        for (int r = 0; r < 4; ++r)
          cm[ti][r] = fmaxf(cm[ti][r],
                            fmaxf(fmaxf(s_acc[ti][0][r], s_acc[ti][1][r]),
                                  fmaxf(s_acc[ti][2][r], s_acc[ti][3][r])));
    }

#pragma unroll
    for (int off = 1; off < 16; off <<= 1)
#pragma unroll
      for (int ti = 0; ti < 2; ++ti)
#pragma unroll
        for (int r = 0; r < 4; ++r) cm[ti][r] = fmaxf(cm[ti][r], __shfl_xor(cm[ti][r], off));
#pragma unroll
    for (int ti = 0; ti < 2; ++ti)
#pragma unroll
      for (int r = 0; r < 4; ++r) m[ti*4 + r] = fmaxf(m[ti*4 + r], cm[ti][r]);

    BARRIER();   // protect Ks/Vs[cur] before next stage overwrites it
  }

  // ================= phase 2: QK^T recompute, p -> (u, l), PV =================
  float lsum[8];
#pragma unroll
  for (int i = 0; i < 8; ++i) lsum[i] = 0.f;

  f32x4 o_acc[2][8];
#pragma unroll
  for (int ti = 0; ti < 2; ++ti)
#pragma unroll
    for (int tj = 0; tj < 8; ++tj) o_acc[ti][tj] = (f32x4){0.f, 0.f, 0.f, 0.f};

  STAGE_K_TO(0, &Ks[0][0]); STAGE_V(0, 0);
  for (int ck = 0; ck < 16; ++ck) {
    const int cur = ck & 1;
    if (ck + 1 < 16) { STAGE_K_TO(ck + 1, &Ks[cur ^ 1][0]); STAGE_V(ck + 1, cur ^ 1); VMCNT(8); }
    else             { VMCNT(0); }
    BARRIER();

    f32x4 s_acc[2][4];
#pragma unroll
    for (int ti = 0; ti < 2; ++ti)
#pragma unroll
      for (int tj = 0; tj < 4; ++tj) s_acc[ti][tj] = (f32x4){0.f, 0.f, 0.f, 0.f};
    __builtin_amdgcn_s_setprio(1);
#pragma unroll
    for (int ks = 0; ks < 4; ++ks)
#pragma unroll
      for (int tj = 0; tj < 4; ++tj) {
        bf16x8 bk = *(const bf16x8*)&Ks[cur][(tj * 16 + l16) * 128 + (((ks * 4 + quad) ^ l16) << 3)];
        s_acc[0][tj] = __builtin_amdgcn_mfma_f32_16x16x32_bf16(qf[0][ks], bk, s_acc[0][tj], 0, 0, 0);
        s_acc[1][tj] = __builtin_amdgcn_mfma_f32_16x16x32_bf16(qf[1][ks], bk, s_acc[1][tj], 0, 0, 0);
      }
    __builtin_amdgcn_s_setprio(0);

#pragma unroll
    for (int ti = 0; ti < 2; ++ti)
#pragma unroll
      for (int tj = 0; tj < 4; ++tj)
#pragma unroll
        for (int r = 0; r < 4; ++r) {
          int ql = ti * 16 + quad * 4 + r;
          int tok = tj * 16 + l16;
          float p = __expf(s_acc[ti][tj][r] - m[ti*4 + r]);
          lsum[ti*4 + r] += p;
          float u = rintf(255.f * p);
          // u is an exact integer in [0,255] -> low 16 mantissa bits are zero
          Ub[w * 2048 + ql * 64 + ((((tok >> 3) ^ (ql & 7)) << 3) | (tok & 7))] =
              (u16)(__float_as_uint(u) >> 16);
        }
#pragma unroll
    for (int ks2 = 0; ks2 < 2; ++ks2) {
      bf16x8 au[2];
#pragma unroll
      for (int ti = 0; ti < 2; ++ti) {
        int ql = ti * 16 + l16;
        au[ti] = *(const bf16x8*)&Ub[w * 2048 + ql * 64 + (((ks2 * 4 + quad) ^ (l16 & 7)) << 3)];
      }
      __builtin_amdgcn_s_setprio(1);
#pragma unroll
      for (int tj = 0; tj < 8; ++tj) {
        bf16x8 bv = *(const bf16x8*)&Vs[cur][(tj * 16 + l16) * 64 + (((ks2 * 4 + quad) ^ (l16 & 7)) << 3)];
        o_acc[0][tj] = __builtin_amdgcn_mfma_f32_16x16x32_bf16(au[0], bv, o_acc[0][tj], 0, 0, 0);
        o_acc[1][tj] = __builtin_amdgcn_mfma_f32_16x16x32_bf16(au[1], bv, o_acc[1][tj], 0, 0, 0);
      }
      __builtin_amdgcn_s_setprio(0);
    }
    BARRIER();   // protect Ks/Vs[cur] before next stage overwrites it
  }
#undef STAGE_K_TO
#undef STAGE_V
#undef STAGE_K2

  // final row-sum reduce across the 16 token-lanes, then 1/(255*l)
#pragma unroll
  for (int off = 1; off < 16; off <<= 1)
#pragma unroll
    for (int i = 0; i < 8; ++i) lsum[i] += __shfl_xor(lsum[i], off);
  float rinv[8];
#pragma unroll
  for (int i = 0; i < 8; ++i) rinv[i] = 1.f / (255.f * lsum[i]);

#pragma unroll
  for (int ti = 0; ti < 2; ++ti)
#pragma unroll
    for (int tj = 0; tj < 8; ++tj)
#pragma unroll
      for (int r = 0; r < 4; ++r) {
        int row = r0 + w * 32 + ti * 16 + quad * 4 + r;
        int d = tj * 16 + l16;
        O[(size_t)row * CDIM + h * HDIM + d] = f2bf(o_acc[ti][tj][r] * rinv[ti*4 + r]);
      }
}

extern "C" void kernel_launch(void* const* d_in, const int* in_sizes, int n_in,
                              void* d_out, int out_size, void* d_ws, size_t ws_size,
                              hipStream_t stream) {
  const float* x    = (const float*)d_in[0];
  const float* cond = (const float*)d_in[1];
  const float* Wq   = (const float*)d_in[2];
  const float* bq   = (const float*)d_in[3];
  const float* Wkv  = (const float*)d_in[4];
  const float* bkv  = (const float*)d_in[5];
  const float* Wp   = (const float*)d_in[6];
  const float* bp   = (const float*)d_in[7];
  float* out = (float*)d_out;

  char* ws = (char*)d_ws;
  size_t off = 0;
  auto alloc = [&](size_t bytes) -> char* {
    char* p = ws + off;
    off += (bytes + 255) & ~(size_t)255;
    return p;
  };
  u16*   Xb    = (u16*)alloc((size_t)NQ * CDIM * 2);
  u16*   Cb    = (u16*)alloc((size_t)NKV * CDIM * 2);
  u16*   WqT   = (u16*)alloc((size_t)CDIM * CDIM * 2);
  u16*   WkvT  = (u16*)alloc((size_t)2 * CDIM * CDIM * 2);
  float* KVraw = (float*)alloc((size_t)NKV * 2 * CDIM * 4);  // only V-half written
  u16*   Qq    = (u16*)alloc((size_t)NQ * CDIM * 2);
  u16*   Kq    = (u16*)alloc((size_t)NKV * CDIM * 2);
  u16*   Vt    = (u16*)alloc((size_t)CDIM * NKV * 2);
  float* vmax  = (float*)alloc((size_t)CDIM * 4);
  u16*   Ob    = (u16*)alloc((size_t)NQ * CDIM * 2);
  u16*   WpT   = (u16*)alloc((size_t)CDIM * CDIM * 2);

  k_prep<<<22536, 256, 0, stream>>>(x, cond, Wq, Wkv, Xb, Cb, WqT, WkvT, (u32*)vmax);
  k_gemm_qkv<<<256, 512, 0, stream>>>(Xb, Cb, WqT, WkvT, Wp, bq, bkv, Qq, Kq, KVraw,
                                      WpT, (u32*)vmax);
  k_vt_quant<<<dim3(CDIM/32, NKV/32), 256, 0, stream>>>(KVraw + CDIM, vmax, Vt);
  k_attn<<<dim3(NQ/128, NHEADS), 256, 0, stream>>>(Qq, Kq, Vt, Ob);
  k_gemm_bt<<<dim3(CDIM/256, NQ/128), 512, 0, stream>>>(Ob, WpT, bp, out, CDIM, CDIM);
}

// Round 11
// 325.906 us; speedup vs baseline: 1.0909x; 1.0068x over previous
//
#include <hip/hip_runtime.h>

typedef unsigned short u16;
typedef unsigned int u32;
typedef __attribute__((ext_vector_type(8))) short bf16x8;
typedef __attribute__((ext_vector_type(4))) float f32x4;

#define NQ 4096      // B*N query tokens
#define NKV 1024     // B*M kv tokens
#define CDIM 2048
#define NHEADS 16
#define HDIM 128
#define QSCALE 0.08838834764831843f  // 1/sqrt(128)

#define GLOAD_LDS16(g, l) __builtin_amdgcn_global_load_lds( \
    (const __attribute__((address_space(1))) unsigned int*)(g), \
    (__attribute__((address_space(3))) unsigned int*)(l), 16, 0, 0)

#define BARRIER() __builtin_amdgcn_s_barrier()
#define VMCNT(n) asm volatile("s_waitcnt vmcnt(" #n ")" ::: "memory")
#define LGKM0() asm volatile("s_waitcnt lgkmcnt(0)" ::: "memory")

__device__ __forceinline__ u16 f2bf(float f) {
  union { float f; u32 u; } a; a.f = f;
  u32 r = (a.u + 0x7fffu + ((a.u >> 16) & 1u)) >> 16;   // RNE
  return (u16)r;
}

// ---------------- fused prep: convert x/cond to bf16, transpose Wq/Wkv, zero vmax --
__global__ __launch_bounds__(256) void k_prep(const float* __restrict__ x,
                                              const float* __restrict__ cond,
                                              const float* __restrict__ Wq,
                                              const float* __restrict__ Wkv,
                                              u16* __restrict__ Xb,
                                              u16* __restrict__ Cb,
                                              u16* __restrict__ WqT,
                                              u16* __restrict__ WkvT,
                                              u32* __restrict__ vmax) {
  __shared__ float tile[32][33];
  const int id = blockIdx.x;
  if (id < 10240) {
    const int nx = NQ * CDIM / 4;
    int i = id * 256 + threadIdx.x;
    const float* in; u16* out; int j;
    if (i < nx) { in = x; out = Xb; j = i; }
    else        { in = cond; out = Cb; j = i - nx; }
    float4 v = ((const float4*)in)[j];
    uint2 r;
    r.x = (u32)f2bf(v.x) | ((u32)f2bf(v.y) << 16);
    r.y = (u32)f2bf(v.z) | ((u32)f2bf(v.w) << 16);
    ((uint2*)out)[j] = r;
    return;
  }
  if (id >= 22528) {
    int i = (id - 22528) * 256 + threadIdx.x;
    if (i < CDIM) vmax[i] = 0u;
    return;
  }
  int id2 = id - 10240;
  const float* in; u16* out; int R, Ccols, bx, by;
  if (id2 < 4096) { in = Wq;  out = WqT;  R = 2048; Ccols = 2048; bx = id2 & 63;  by = id2 >> 6; }
  else            { int i = id2 - 4096; in = Wkv; out = WkvT; R = 2048; Ccols = 4096; bx = i & 127; by = i >> 7; }
  int c0 = bx * 32, r0 = by * 32;
  int tx = threadIdx.x & 31, ty = threadIdx.x >> 5;
#pragma unroll
  for (int i = 0; i < 4; ++i)
    tile[ty + i*8][tx] = in[(size_t)(r0 + ty + i*8) * Ccols + c0 + tx];
  __syncthreads();
#pragma unroll
  for (int i = 0; i < 4; ++i)
    out[(size_t)(c0 + ty + i*8) * R + r0 + tx] = f2bf(tile[tx][ty + i*8]);
}

// ======================================================================
// 256x256-tile, BK=64, 8-wave, 4-phase/K-tile bf16 GEMM core (R3-proven).
// XOR-swizzled LDS via pre-swizzled global source; counted vmcnt(4) at
// tile boundary (never 0 in steady state). Bit-identical MFMA K-order.
// ======================================================================
__device__ __forceinline__ void gemm256_core(const u16* __restrict__ Ap,
                                             const u16* __restrict__ Bp,
                                             int lda, int ldb, int NT,
                                             u16* __restrict__ la0, u16* __restrict__ la1,
                                             u16* __restrict__ lb0, u16* __restrict__ lb1,
                                             f32x4 (&acc)[8][4]) {
  const int tid = threadIdx.x;
  const int lane = tid & 63, w = tid >> 6, quad = lane >> 4, l16 = lane & 15;
  const int wr = w >> 2, wc = w & 3;
  const int xo = (l16 & 7) << 4;                 // ds_read byte XOR
  const int rA = tid >> 3;                       // staging row 0..63 within half
  const int cbu = ((((tid & 7) << 4) ^ ((rA & 7) << 4)) >> 1);  // pre-swizzled src col (u16)

  bf16x8 a[4][2];
  bf16x8 bb[2][2][2];

#define STAGE(P, ld, L, h, tt) do { \
    const u16* g0_ = (P) + (size_t)((h) * 128 + rA) * (ld) + (size_t)(tt) * 64 + cbu; \
    u16* l0_ = (L) + (h) * 8192 + w * 512; \
    GLOAD_LDS16(g0_, l0_); \
    GLOAD_LDS16(g0_ + (size_t)64 * (ld), l0_ + 4096); \
  } while (0)

#define RD_A(bufp, mh) { \
    _Pragma("unroll") for (int rf = 0; rf < 4; ++rf) \
      _Pragma("unroll") for (int ks = 0; ks < 2; ++ks) \
        a[rf][ks] = *(const bf16x8*)((const char*)(bufp) + \
          (size_t)(wr * 128 + (mh) * 64 + rf * 16 + l16) * 128 + ((ks * 64 + quad * 16) ^ xo)); }

#define RD_B(bufp, nh) { \
    _Pragma("unroll") for (int cf = 0; cf < 2; ++cf) \
      _Pragma("unroll") for (int ks = 0; ks < 2; ++ks) \
        bb[nh][cf][ks] = *(const bf16x8*)((const char*)(bufp) + \
          (size_t)(wc * 64 + (nh) * 32 + cf * 16 + l16) * 128 + ((ks * 64 + quad * 16) ^ xo)); }

#define MQ(mh, nh) { \
    __builtin_amdgcn_s_setprio(1); \
    _Pragma("unroll") for (int rf = 0; rf < 4; ++rf) \
      _Pragma("unroll") for (int cf = 0; cf < 2; ++cf) \
        _Pragma("unroll") for (int ks = 0; ks < 2; ++ks) \
          acc[(mh)*4+rf][(nh)*2+cf] = __builtin_amdgcn_mfma_f32_16x16x32_bf16( \
            a[rf][ks], bb[nh][cf][ks], acc[(mh)*4+rf][(nh)*2+cf], 0, 0, 0); \
    __builtin_amdgcn_s_setprio(0); }

  STAGE(Bp, ldb, lb0, 0, 0);
  STAGE(Bp, ldb, lb0, 1, 0);
  STAGE(Ap, lda, la0, 0, 0);
  STAGE(Ap, lda, la0, 1, 0);
  STAGE(Bp, ldb, lb1, 0, 1);
  STAGE(Bp, ldb, lb1, 1, 1);
  VMCNT(4);
  BARRIER();

  for (int t = 0; t < NT; ++t) {
    u16* Ab = (t & 1) ? la1 : la0;
    u16* Bb = (t & 1) ? lb1 : lb0;
    u16* An = (t & 1) ? la0 : la1;
    const bool s1 = (t + 1) < NT, s2 = (t + 2) < NT;
    // ph0
    RD_A(Ab, 0); RD_B(Bb, 0);
    if (s1) STAGE(Ap, lda, An, 0, t + 1);
    BARRIER(); LGKM0();
    MQ(0, 0);
    BARRIER();
    // ph1
    RD_B(Bb, 1);
    if (s1) STAGE(Ap, lda, An, 1, t + 1);
    BARRIER(); LGKM0();
    MQ(0, 1);
    BARRIER();
    // ph2
    RD_A(Ab, 1);
    if (s2) STAGE(Bp, ldb, Bb, 0, t + 2);
    BARRIER(); LGKM0();
    MQ(1, 1);
    BARRIER();
    // ph3
    if (s2) STAGE(Bp, ldb, Bb, 1, t + 2);
    MQ(1, 0);
    if (s2) { VMCNT(4); } else { VMCNT(0); }
    BARRIER();
  }
  VMCNT(0);
#undef STAGE
#undef RD_A
#undef RD_B
#undef MQ
}

// ---------------- bf16 MFMA GEMM (out-proj), BM=128 x BN=256, full K, direct out --
__global__ __launch_bounds__(512, 2) void k_gemm_bt(const u16* __restrict__ A,
                                                    const u16* __restrict__ Bt,
                                                    const float* __restrict__ bias,
                                                    float* __restrict__ Cout,
                                                    int Ndim, int Kdim) {
  __shared__ u16 la0[8192];
  __shared__ u16 la1[8192];
  __shared__ u16 lb0[16384];
  __shared__ u16 lb1[16384];
  const int bn = blockIdx.x, bm = blockIdx.y;
  const int tid = threadIdx.x;
  const int lane = tid & 63, w = tid >> 6, quad = lane >> 4, l16 = lane & 15;
  const int wr = w >> 2, wc = w & 3;
  const int xo = (l16 & 7) << 4;
  const int rA = tid >> 3;
  const int cbu = ((((tid & 7) << 4) ^ ((rA & 7) << 4)) >> 1);

  const u16* Ap = A + (size_t)bm * 128 * Kdim;
  const u16* Bp = Bt + (size_t)bn * 256 * Kdim;
  const int NT = Kdim >> 6;

  f32x4 acc[4][4];
#pragma unroll
  for (int i = 0; i < 4; ++i)
#pragma unroll
    for (int j = 0; j < 4; ++j) acc[i][j] = (f32x4){0.f, 0.f, 0.f, 0.f};

  bf16x8 a[4][2];
  bf16x8 bb[2][2][2];

#define STAGE_A(L, tt) do { \
    const u16* g0_ = Ap + (size_t)rA * Kdim + (size_t)(tt) * 64 + cbu; \
    u16* l0_ = (L) + w * 512; \
    GLOAD_LDS16(g0_, l0_); \
    GLOAD_LDS16(g0_ + (size_t)64 * Kdim, l0_ + 4096); \
  } while (0)

#define STAGE_B(L, h, tt) do { \
    const u16* g0_ = Bp + (size_t)((h) * 128 + rA) * Kdim + (size_t)(tt) * 64 + cbu; \
    u16* l0_ = (L) + (h) * 8192 + w * 512; \
    GLOAD_LDS16(g0_, l0_); \
    GLOAD_LDS16(g0_ + (size_t)64 * Kdim, l0_ + 4096); \
  } while (0)

#define RD_A2(bufp) { \
    _Pragma("unroll") for (int rf = 0; rf < 4; ++rf) \
      _Pragma("unroll") for (int ks = 0; ks < 2; ++ks) \
        a[rf][ks] = *(const bf16x8*)((const char*)(bufp) + \
          (size_t)(wr * 64 + rf * 16 + l16) * 128 + ((ks * 64 + quad * 16) ^ xo)); }

#define RD_B2(bufp, nh) { \
    _Pragma("unroll") for (int cf = 0; cf < 2; ++cf) \
      _Pragma("unroll") for (int ks = 0; ks < 2; ++ks) \
        bb[nh][cf][ks] = *(const bf16x8*)((const char*)(bufp) + \
          (size_t)(wc * 64 + (nh) * 32 + cf * 16 + l16) * 128 + ((ks * 64 + quad * 16) ^ xo)); }

#define MQ2(nh) { \
    __builtin_amdgcn_s_setprio(1); \
    _Pragma("unroll") for (int rf = 0; rf < 4; ++rf) \
      _Pragma("unroll") for (int cf = 0; cf < 2; ++cf) \
        _Pragma("unroll") for (int ks = 0; ks < 2; ++ks) \
          acc[rf][(nh)*2+cf] = __builtin_amdgcn_mfma_f32_16x16x32_bf16( \
            a[rf][ks], bb[nh][cf][ks], acc[rf][(nh)*2+cf], 0, 0, 0); \
    __builtin_amdgcn_s_setprio(0); }

  STAGE_A(la0, 0);
  STAGE_B(lb0, 0, 0);
  STAGE_B(lb0, 1, 0);
  STAGE_B(lb1, 0, 1);
  STAGE_B(lb1, 1, 1);
  VMCNT(4);
  BARRIER();

  for (int t = 0; t < NT; ++t) {
    u16* Ab = (t & 1) ? la1 : la0;
    u16* Bb = (t & 1) ? lb1 : lb0;
    u16* An = (t & 1) ? la0 : la1;
    const bool s1 = (t + 1) < NT, s2 = (t + 2) < NT;
    // ph0: read A(all) + B(nh0); stage A(t+1) -> other A buf; MFMA nh0
    RD_A2(Ab); RD_B2(Bb, 0);
    if (s1) STAGE_A(An, t + 1);
    BARRIER(); LGKM0();
    MQ2(0);
    BARRIER();
    // ph1: read B(nh1); all waves' Bb reads retired -> stage B(t+2) into Bb
    RD_B2(Bb, 1);
    LGKM0();
    BARRIER();
    if (s2) { STAGE_B(Bb, 0, t + 2); STAGE_B(Bb, 1, t + 2); }
    MQ2(1);
    if (s2) { VMCNT(4); } else { VMCNT(0); }
    BARRIER();
  }
  VMCNT(0);
#undef STAGE_A
#undef STAGE_B
#undef RD_A2
#undef RD_B2
#undef MQ2

#pragma unroll
  for (int mf = 0; mf < 4; ++mf) {
    int row = bm * 128 + wr * 64 + mf * 16 + quad * 4;
#pragma unroll
    for (int nf = 0; nf < 4; ++nf) {
      int col = bn * 256 + wc * 64 + nf * 16 + l16;
      float bv = bias[col];
#pragma unroll
      for (int r = 0; r < 4; ++r)
        Cout[(size_t)(row + r) * Ndim + col] = acc[mf][nf][r] + bv;
    }
  }
}

// ---------------- fused QKV projection GEMM + quant epilogue + V colmax + Wp filler --
__global__ __launch_bounds__(512, 2) void k_gemm_qkv(const u16* __restrict__ Xb,
                                                     const u16* __restrict__ Cb,
                                                     const u16* __restrict__ WqT,
                                                     const u16* __restrict__ WkvT,
                                                     const float* __restrict__ Wp,
                                                     const float* __restrict__ bq,
                                                     const float* __restrict__ bkv,
                                                     u16* __restrict__ Qq,
                                                     u16* __restrict__ Kq,
                                                     float* __restrict__ Vraw,
                                                     u16* __restrict__ WpT,
                                                     u32* __restrict__ vmax) {
  __shared__ u16 la0[16384];
  __shared__ u16 la1[16384];
  __shared__ u16 lb0[16384];
  __shared__ u16 lb1[16384];

  const int id = blockIdx.x;
  const int tid = threadIdx.x;

  if (id >= 192) {
    // ---- Wp transpose filler: 64 blocks x 16 tiles of 64x64 (73-pad: no conflicts) --
    int fid = id - 192;
    float (*ft)[73] = (float(*)[73])la0;   // 64x73 fp32 = 18.7KB, aliases GEMM LDS
    const int rr = tid >> 3, cb = (tid & 7) * 8;
    for (int i = 0; i < 16; ++i) {
      int tIdx = fid * 16 + i;
      int r0 = (tIdx >> 5) * 64, c0 = (tIdx & 31) * 64;
      __syncthreads();
#pragma unroll
      for (int j = 0; j < 2; ++j)
        *(float4*)&ft[rr][cb + j * 4] =
            *(const float4*)&Wp[(size_t)(r0 + rr) * 2048 + c0 + cb + j * 4];
      __syncthreads();
      u16 tmp[8];
#pragma unroll
      for (int j = 0; j < 8; ++j) tmp[j] = f2bf(ft[cb + j][rr]);
      *(uint4*)&WpT[(size_t)(c0 + rr) * 2048 + r0 + cb] = *(uint4*)tmp;
    }
    return;
  }

  const u16 *Ain; const u16 *Bt; const float* bias;
  u16* out16 = nullptr; float* outf = nullptr;
  int bm, bn, ostride, ocol;
  float premul = 1.0f;
  if (id < 128) {
    bm = id >> 3; bn = id & 7;
    Ain = Xb; Bt = WqT + (size_t)(bn * 256) * CDIM;
    bias = bq + bn * 256; out16 = Qq; ostride = CDIM; ocol = bn * 256;
    premul = QSCALE;
  } else if (id < 160) {
    int i2 = id - 128; bm = i2 >> 3; bn = i2 & 7;
    Ain = Cb; Bt = WkvT + (size_t)(bn * 256) * CDIM;
    bias = bkv + bn * 256; out16 = Kq; ostride = CDIM; ocol = bn * 256;
  } else {
    int i3 = id - 160; bm = i3 >> 3; bn = i3 & 7;
    Ain = Cb; Bt = WkvT + (size_t)(2048 + bn * 256) * CDIM;
    bias = bkv + 2048 + bn * 256; outf = Vraw; ostride = 2 * CDIM; ocol = 2048 + bn * 256;
  }

  f32x4 acc[8][4];
#pragma unroll
  for (int i = 0; i < 8; ++i)
#pragma unroll
    for (int j = 0; j < 4; ++j) acc[i][j] = (f32x4){0.f, 0.f, 0.f, 0.f};

  gemm256_core(Ain + (size_t)bm * 256 * CDIM, Bt, CDIM, CDIM, CDIM >> 6,
               la0, la1, lb0, lb1, acc);

  const int w = tid >> 6, lane = tid & 63, quad = lane >> 4, l16 = lane & 15;
  const int wr = w >> 2, wc = w & 3;

  float bv[4];
#pragma unroll
  for (int nf = 0; nf < 4; ++nf) bv[nf] = bias[wc * 64 + nf * 16 + l16];

  if (outf) {
    float cmax[4];
#pragma unroll
    for (int nf = 0; nf < 4; ++nf) cmax[nf] = 0.f;
#pragma unroll
    for (int mf = 0; mf < 8; ++mf) {
      int row = bm * 256 + wr * 128 + mf * 16 + quad * 4;
#pragma unroll
      for (int nf = 0; nf < 4; ++nf) {
        int col = ocol + wc * 64 + nf * 16 + l16;
#pragma unroll
        for (int r = 0; r < 4; ++r) {
          float v = acc[mf][nf][r] + bv[nf];
          outf[(size_t)(row + r) * ostride + col] = v;
          cmax[nf] = fmaxf(cmax[nf], fabsf(v));
        }
      }
    }
#pragma unroll
    for (int nf = 0; nf < 4; ++nf) {
      cmax[nf] = fmaxf(cmax[nf], __shfl_xor(cmax[nf], 16));
      cmax[nf] = fmaxf(cmax[nf], __shfl_xor(cmax[nf], 32));
    }
    if (quad == 0) {
#pragma unroll
      for (int nf = 0; nf < 4; ++nf)
        atomicMax(&vmax[(ocol - 2048) + wc * 64 + nf * 16 + l16],
                  __float_as_uint(cmax[nf]));
    }
    return;
  }

  // Q/K: fused per-row-128 symmetric int8 fake-quant
  float amax[8][4];
#pragma unroll
  for (int mf = 0; mf < 8; ++mf)
#pragma unroll
    for (int r = 0; r < 4; ++r) amax[mf][r] = 0.f;
#pragma unroll
  for (int mf = 0; mf < 8; ++mf)
#pragma unroll
    for (int nf = 0; nf < 4; ++nf)
#pragma unroll
      for (int r = 0; r < 4; ++r) {
        float v = (acc[mf][nf][r] + bv[nf]) * premul;
        acc[mf][nf][r] = v;
        amax[mf][r] = fmaxf(amax[mf][r], fabsf(v));
      }
#pragma unroll
  for (int off = 1; off < 16; off <<= 1)
#pragma unroll
    for (int mf = 0; mf < 8; ++mf)
#pragma unroll
      for (int r = 0; r < 4; ++r)
        amax[mf][r] = fmaxf(amax[mf][r], __shfl_xor(amax[mf][r], off));

  float (*rmax)[256] = (float(*)[256])(&la0[0]);
  if (l16 == 0)
#pragma unroll
    for (int mf = 0; mf < 8; ++mf)
#pragma unroll
      for (int r = 0; r < 4; ++r)
        rmax[wc][wr * 128 + mf * 16 + quad * 4 + r] = amax[mf][r];
  __syncthreads();

  const int g2 = (wc >> 1) << 1;
#pragma unroll
  for (int mf = 0; mf < 8; ++mf) {
    int rowl = wr * 128 + mf * 16 + quad * 4;
    int row = bm * 256 + rowl;
#pragma unroll
    for (int r = 0; r < 4; ++r) {
      float s = fmaxf(fmaxf(rmax[g2][rowl + r], rmax[g2 + 1][rowl + r]) * (1.f / 127.f), 1e-8f);
#pragma unroll
      for (int nf = 0; nf < 4; ++nf) {
        int col = ocol + wc * 64 + nf * 16 + l16;
        float q = fminf(fmaxf(rintf(acc[mf][nf][r] / s), -127.f), 127.f) * s;
        out16[(size_t)(row + r) * ostride + col] = f2bf(q);
      }
    }
  }
}

// ---------------- quantize V and write transposed: Vt[(h*128+d)][token] ----------------
__global__ __launch_bounds__(256) void k_vt_quant(const float* __restrict__ in,
                                                  const float* __restrict__ vmax,
                                                  u16* __restrict__ Vt) {
  __shared__ float tile[32][33];
  int c0 = blockIdx.x * 32;
  int t0 = blockIdx.y * 32;
  int tx = threadIdx.x & 31, ty = threadIdx.x >> 5;
#pragma unroll
  for (int i = 0; i < 4; ++i)
    tile[ty + i*8][tx] = in[(size_t)(t0 + ty + i*8) * 4096 + c0 + tx];
  __syncthreads();
#pragma unroll
  for (int i = 0; i < 4; ++i) {
    int d = ty + i*8;
    float s = fmaxf(vmax[c0 + d] * (1.f / 127.f), 1e-8f);
    float q = fminf(fmaxf(rintf(tile[tx][d] / s), -127.f), 127.f) * s;
    Vt[(size_t)(c0 + d) * 1024 + t0 + tx] = f2bf(q);
  }
}

// ---------------- single-pass online-softmax attention ----------------------------
// Per 64-token chunk: QK^T -> chunk row-max cm -> mn = max(m, cm); rescale o_acc
// and lsum by exp(m-mn) (exactly 1.0 once the max settles); p = exp(s-mn);
// u = rint(255p) (stale-max rounding on early chunks only, |du|<=1) -> Ub -> PV.
// First chunk: exp(-3e38 - mn) = 0 cleanly zeroes the empty state. MFMA count
// 1024/wave (was 1536); K staged once (was twice); 32 barriers (was 48).
__global__ __launch_bounds__(256, 2) void k_attn(const u16* __restrict__ Qq,
                                                 const u16* __restrict__ Kq,
                                                 const u16* __restrict__ Vt,
                                                 u16* __restrict__ O) {
  __shared__ u16 Ks[2][64 * 128];  // dbuf, swizzle g^(tok&15), 32KB
  __shared__ u16 Vs[2][128 * 64];  // dbuf, swizzle g^(d&7),   32KB
  __shared__ u16 Ub[4 * 32 * 64];  // per-wave u tile, swizzle g^(q&7), 16KB

  const int h = blockIdx.y;
  const int r0 = blockIdx.x * 128;
  const int t = threadIdx.x;
  const int w = t >> 6, lane = t & 63, quad = lane >> 4, l16 = lane & 15;

  const u16* Qh = Qq + (size_t)(r0 + w * 32) * CDIM + h * HDIM;
  const u16* Kh = Kq + h * HDIM;
  const u16* Vh = Vt + (size_t)h * HDIM * NKV;

  bf16x8 qf[2][4];
#pragma unroll
  for (int ti = 0; ti < 2; ++ti)
#pragma unroll
    for (int ks = 0; ks < 4; ++ks)
      qf[ti][ks] = *(const bf16x8*)&Qh[(size_t)(ti * 16 + l16) * CDIM + ks * 32 + quad * 8];

  const int ktl = (w * 4) * 4 + (lane >> 4);
  const int kg = (lane & 15);
  const int vdl = (w * 4) * 8 + (lane >> 3);
  const int vg = (lane & 7);

#define STAGE_K(ck, b) { \
    _Pragma("unroll") for (int j = 0; j < 4; ++j) { \
      int tok = ktl + j * 4; \
      GLOAD_LDS16(Kh + (size_t)((ck) * 64 + tok) * CDIM + (kg ^ (tok & 15)) * 8, \
                  &Ks[b][(w * 4 + j) * 512]); \
    } }
#define STAGE_V(ck, b) { \
    _Pragma("unroll") for (int j = 0; j < 4; ++j) { \
      int dl = vdl + j * 8; \
      GLOAD_LDS16(Vh + (size_t)dl * NKV + (ck) * 64 + (vg ^ (dl & 7)) * 8, \
                  &Vs[b][(w * 4 + j) * 512]); \
    } }

  float m[8], lsum[8];
#pragma unroll
  for (int i = 0; i < 8; ++i) { m[i] = -3e38f; lsum[i] = 0.f; }

  f32x4 o_acc[2][8];
#pragma unroll
  for (int ti = 0; ti < 2; ++ti)
#pragma unroll
    for (int tj = 0; tj < 8; ++tj) o_acc[ti][tj] = (f32x4){0.f, 0.f, 0.f, 0.f};

  STAGE_K(0, 0); STAGE_V(0, 0);
  for (int ck = 0; ck < 16; ++ck) {
    const int cur = ck & 1;
    if (ck + 1 < 16) { STAGE_K(ck + 1, cur ^ 1); STAGE_V(ck + 1, cur ^ 1); VMCNT(8); }
    else             { VMCNT(0); }
    BARRIER();

    // ---- QK^T ----
    f32x4 s_acc[2][4];
#pragma unroll
    for (int ti = 0; ti < 2; ++ti)
#pragma unroll
      for (int tj = 0; tj < 4; ++tj) s_acc[ti][tj] = (f32x4){0.f, 0.f, 0.f, 0.f};
    __builtin_amdgcn_s_setprio(1);
#pragma unroll
    for (int ks = 0; ks < 4; ++ks)
#pragma unroll
      for (int tj = 0; tj < 4; ++tj) {
        bf16x8 bk = *(const bf16x8*)&Ks[cur][(tj * 16 + l16) * 128 + (((ks * 4 + quad) ^ l16) << 3)];
        s_acc[0][tj] = __builtin_amdgcn_mfma_f32_16x16x32_bf16(qf[0][ks], bk, s_acc[0][tj], 0, 0, 0);
        s_acc[1][tj] = __builtin_amdgcn_mfma_f32_16x16x32_bf16(qf[1][ks], bk, s_acc[1][tj], 0, 0, 0);
      }
    __builtin_amdgcn_s_setprio(0);

    // ---- chunk row-max + online rescale ----
    float scl[8];
#pragma unroll
    for (int ti = 0; ti < 2; ++ti) {
      float cm[4];
#pragma unroll
      for (int r = 0; r < 4; ++r)
        cm[r] = fmaxf(fmaxf(s_acc[ti][0][r], s_acc[ti][1][r]),
                      fmaxf(s_acc[ti][2][r], s_acc[ti][3][r]));
#pragma unroll
      for (int off = 1; off < 16; off <<= 1)
#pragma unroll
        for (int r = 0; r < 4; ++r) cm[r] = fmaxf(cm[r], __shfl_xor(cm[r], off));
#pragma unroll
      for (int r = 0; r < 4; ++r) {
        float mn = fmaxf(m[ti*4 + r], cm[r]);
        scl[ti*4 + r] = __expf(m[ti*4 + r] - mn);
        m[ti*4 + r] = mn;
      }
    }
#pragma unroll
    for (int i = 0; i < 8; ++i) lsum[i] *= scl[i];
#pragma unroll
    for (int ti = 0; ti < 2; ++ti)
#pragma unroll
      for (int tj = 0; tj < 8; ++tj)
#pragma unroll
        for (int r = 0; r < 4; ++r) o_acc[ti][tj][r] *= scl[ti*4 + r];

    // ---- p -> (u, lsum) ----
#pragma unroll
    for (int ti = 0; ti < 2; ++ti)
#pragma unroll
      for (int tj = 0; tj < 4; ++tj)
#pragma unroll
        for (int r = 0; r < 4; ++r) {
          int ql = ti * 16 + quad * 4 + r;
          int tok = tj * 16 + l16;
          float p = __expf(s_acc[ti][tj][r] - m[ti*4 + r]);
          lsum[ti*4 + r] += p;
          float u = rintf(255.f * p);
          // u is an exact integer in [0,255] -> low 16 mantissa bits are zero
          Ub[w * 2048 + ql * 64 + ((((tok >> 3) ^ (ql & 7)) << 3) | (tok & 7))] =
              (u16)(__float_as_uint(u) >> 16);
        }

    // ---- PV ----
#pragma unroll
    for (int ks2 = 0; ks2 < 2; ++ks2) {
      bf16x8 au[2];
#pragma unroll
      for (int ti = 0; ti < 2; ++ti) {
        int ql = ti * 16 + l16;
        au[ti] = *(const bf16x8*)&Ub[w * 2048 + ql * 64 + (((ks2 * 4 + quad) ^ (l16 & 7)) << 3)];
      }
      __builtin_amdgcn_s_setprio(1);
#pragma unroll
      for (int tj = 0; tj < 8; ++tj) {
        bf16x8 bv = *(const bf16x8*)&Vs[cur][(tj * 16 + l16) * 64 + (((ks2 * 4 + quad) ^ (l16 & 7)) << 3)];
        o_acc[0][tj] = __builtin_amdgcn_mfma_f32_16x16x32_bf16(au[0], bv, o_acc[0][tj], 0, 0, 0);
        o_acc[1][tj] = __builtin_amdgcn_mfma_f32_16x16x32_bf16(au[1], bv, o_acc[1][tj], 0, 0, 0);
      }
      __builtin_amdgcn_s_setprio(0);
    }
    BARRIER();   // protect Ks/Vs[cur] before next stage overwrites it
  }
#undef STAGE_K
#undef STAGE_V

  // final row-sum reduce across the 16 token-lanes, then 1/(255*l)
#pragma unroll
  for (int off = 1; off < 16; off <<= 1)
#pragma unroll
    for (int i = 0; i < 8; ++i) lsum[i] += __shfl_xor(lsum[i], off);
  float rinv[8];
#pragma unroll
  for (int i = 0; i < 8; ++i) rinv[i] = 1.f / (255.f * lsum[i]);

#pragma unroll
  for (int ti = 0; ti < 2; ++ti)
#pragma unroll
    for (int tj = 0; tj < 8; ++tj)
#pragma unroll
      for (int r = 0; r < 4; ++r) {
        int row = r0 + w * 32 + ti * 16 + quad * 4 + r;
        int d = tj * 16 + l16;
        O[(size_t)row * CDIM + h * HDIM + d] = f2bf(o_acc[ti][tj][r] * rinv[ti*4 + r]);
      }
}

extern "C" void kernel_launch(void* const* d_in, const int* in_sizes, int n_in,
                              void* d_out, int out_size, void* d_ws, size_t ws_size,
                              hipStream_t stream) {
  const float* x    = (const float*)d_in[0];
  const float* cond = (const float*)d_in[1];
  const float* Wq   = (const float*)d_in[2];
  const float* bq   = (const float*)d_in[3];
  const float* Wkv  = (const float*)d_in[4];
  const float* bkv  = (const float*)d_in[5];
  const float* Wp   = (const float*)d_in[6];
  const float* bp   = (const float*)d_in[7];
  float* out = (float*)d_out;

  char* ws = (char*)d_ws;
  size_t off = 0;
  auto alloc = [&](size_t bytes) -> char* {
    char* p = ws + off;
    off += (bytes + 255) & ~(size_t)255;
    return p;
  };
  u16*   Xb    = (u16*)alloc((size_t)NQ * CDIM * 2);
  u16*   Cb    = (u16*)alloc((size_t)NKV * CDIM * 2);
  u16*   WqT   = (u16*)alloc((size_t)CDIM * CDIM * 2);
  u16*   WkvT  = (u16*)alloc((size_t)2 * CDIM * CDIM * 2);
  float* KVraw = (float*)alloc((size_t)NKV * 2 * CDIM * 4);  // only V-half written
  u16*   Qq    = (u16*)alloc((size_t)NQ * CDIM * 2);
  u16*   Kq    = (u16*)alloc((size_t)NKV * CDIM * 2);
  u16*   Vt    = (u16*)alloc((size_t)CDIM * NKV * 2);
  float* vmax  = (float*)alloc((size_t)CDIM * 4);
  u16*   Ob    = (u16*)alloc((size_t)NQ * CDIM * 2);
  u16*   WpT   = (u16*)alloc((size_t)CDIM * CDIM * 2);

  k_prep<<<22536, 256, 0, stream>>>(x, cond, Wq, Wkv, Xb, Cb, WqT, WkvT, (u32*)vmax);
  k_gemm_qkv<<<256, 512, 0, stream>>>(Xb, Cb, WqT, WkvT, Wp, bq, bkv, Qq, Kq, KVraw,
                                      WpT, (u32*)vmax);
  k_vt_quant<<<dim3(CDIM/32, NKV/32), 256, 0, stream>>>(KVraw + CDIM, vmax, Vt);
  k_attn<<<dim3(NQ/128, NHEADS), 256, 0, stream>>>(Qq, Kq, Vt, Ob);
  k_gemm_bt<<<dim3(CDIM/256, NQ/128), 512, 0, stream>>>(Ob, WpT, bp, out, CDIM, CDIM);
}